// Round 2
// baseline (524.157 us; speedup 1.0000x reference)
//
#include <hip/hip_runtime.h>

#define BATCH 8
#define NTOK 1032
#define NPAD 1088
#define MTOT (BATCH*NTOK)   // 8256
#define MPAD 8320           // 65 * 128

typedef __bf16 bf16x8 __attribute__((ext_vector_type(8)));
typedef float f32x4 __attribute__((ext_vector_type(4)));
typedef unsigned short us8 __attribute__((ext_vector_type(8)));
typedef unsigned short us4 __attribute__((ext_vector_type(4)));

__device__ __forceinline__ unsigned short f2bf(float f){
  unsigned int u = __builtin_bit_cast(unsigned int, f);
  u += 0x7fffu + ((u >> 16) & 1u);          // RNE
  return (unsigned short)(u >> 16);
}

#define MFMA16(a,b,c) __builtin_amdgcn_mfma_f32_16x16x32_bf16( \
    __builtin_bit_cast(bf16x8,(a)), __builtin_bit_cast(bf16x8,(b)), (c), 0, 0, 0)

// async global->LDS, 16B per lane, dest = wave-uniform base + lane*16
__device__ __forceinline__ void gl_lds16(const unsigned short* g, unsigned short* l){
  __builtin_amdgcn_global_load_lds(
      (const __attribute__((address_space(1))) unsigned int*)g,
      (__attribute__((address_space(3))) unsigned int*)l, 16, 0, 0);
}

// ---------------- fp32 -> bf16 conversion ----------------
__global__ __launch_bounds__(256) void cvt_f32_bf16(const float* __restrict__ in,
                                                    unsigned short* __restrict__ out, int n4){
  int i = blockIdx.x * 256 + threadIdx.x;
  if (i < n4){
    float4 v = reinterpret_cast<const float4*>(in)[i];
    us4 o; o.x = f2bf(v.x); o.y = f2bf(v.y); o.z = f2bf(v.z); o.w = f2bf(v.w);
    reinterpret_cast<us4*>(out)[i] = o;
  }
}

// ---------------- zero all padded regions ----------------
__global__ __launch_bounds__(256) void pad_zero(unsigned short* __restrict__ qb,
                                                unsigned short* __restrict__ kb,
                                                unsigned short* __restrict__ vt,
                                                unsigned short* __restrict__ xb,
                                                unsigned short* __restrict__ ao){
  int i = blockIdx.x * 256 + threadIdx.x;
  const int t1 = 128 * (NPAD - NTOK) * 64;          // q/k/v pad rows
  const int t2 = t1 + (MPAD - MTOT) * 1024;         // x_bf pad rows
  const int t3 = t2 + (MPAD - MTOT) * 1024;         // aout pad rows
  if (i < t1){
    int bh = i / ((NPAD - NTOK) * 64);
    int r  = (i / 64) % (NPAD - NTOK);
    int d  = i % 64;
    int idx = (bh * NPAD + NTOK + r) * 64 + d;
    qb[idx] = 0;
    kb[idx] = 0;
    vt[(bh * 64 + d) * NPAD + NTOK + r] = 0;
  } else if (i < t2){
    xb[(size_t)MTOT * 1024 + (i - t1)] = 0;
  } else if (i < t3){
    ao[(size_t)MTOT * 1024 + (i - t2)] = 0;
  }
}

// ---------------- QKV GEMM (m97 structure): C[MPAD][3072] = A * W^T ----------------
__global__ __launch_bounds__(256,2) void qkv_gemm(
    const unsigned short* __restrict__ A,   // [MPAD][1024] bf16
    const unsigned short* __restrict__ Bw,  // [3072][1024] bf16
    const float* __restrict__ bias,         // [3072]
    unsigned short* __restrict__ qb,        // [128][NPAD][64]
    unsigned short* __restrict__ kb,        // [128][NPAD][64]
    unsigned short* __restrict__ vt)        // [128][64][NPAD]
{
  const int K = 1024;
  __shared__ __align__(16) unsigned short As[128*32];
  __shared__ __align__(16) unsigned short Bs[128*32];
  int tid = threadIdx.x;
  int m0 = blockIdx.y * 128, n0 = blockIdx.x * 128;
  int w = tid >> 6, lane = tid & 63, lr = lane & 15, lg = lane >> 4;
  int wr = w >> 1, wc = w & 1;
  int srow = lane >> 2, scol = (lane & 3) * 8;
  f32x4 acc[4][4] = {};

  for (int k0 = 0; k0 < K; k0 += 32){
    __syncthreads();
    #pragma unroll
    for (int i = 0; i < 2; i++){
      int q = w * 2 + i;                       // 8 chunks of 16 rows
      gl_lds16(&A [(size_t)(m0 + q*16 + srow) * K + k0 + scol], &As[q*512]);
      gl_lds16(&Bw[(size_t)(n0 + q*16 + srow) * K + k0 + scol], &Bs[q*512]);
    }
    __syncthreads();
    us8 a[4], b[4];
    #pragma unroll
    for (int mi = 0; mi < 4; mi++) a[mi] = *reinterpret_cast<const us8*>(&As[(wr*64 + mi*16 + lr)*32 + lg*8]);
    #pragma unroll
    for (int ni = 0; ni < 4; ni++) b[ni] = *reinterpret_cast<const us8*>(&Bs[(wc*64 + ni*16 + lr)*32 + lg*8]);
    #pragma unroll
    for (int mi = 0; mi < 4; mi++)
      #pragma unroll
      for (int ni = 0; ni < 4; ni++)
        acc[mi][ni] = MFMA16(a[mi], b[ni], acc[mi][ni]);
  }

  // epilogue: scatter into q/k [bh][n][64] and v transposed [bh][64][n]
  #pragma unroll
  for (int mi = 0; mi < 4; mi++){
    #pragma unroll
    for (int ni = 0; ni < 4; ni++){
      #pragma unroll
      for (int reg = 0; reg < 4; reg++){
        int m = m0 + wr*64 + mi*16 + lg*4 + reg;
        if (m >= MTOT) continue;
        int n = n0 + wc*64 + ni*16 + lr;
        float val = acc[mi][ni][reg] + bias[n];
        int b_ = m / NTOK, nidx = m % NTOK;
        int t = n >> 10, h = (n >> 6) & 15, d = n & 63;
        int bh = h * BATCH + b_;
        unsigned short bv = f2bf(val);
        if (t == 0)      qb[(size_t)(bh * NPAD + nidx) * 64 + d] = bv;
        else if (t == 1) kb[(size_t)(bh * NPAD + nidx) * 64 + d] = bv;
        else             vt[(size_t)(bh * 64 + d) * NPAD + nidx] = bv;
      }
    }
  }
}

// ---------------- flash attention with compacted decomposed rel-pos ----------------
__global__ __launch_bounds__(256,6) void attn_kernel(
    const unsigned short* __restrict__ qb,
    const unsigned short* __restrict__ kb,
    const unsigned short* __restrict__ vt,
    const float* __restrict__ rph,   // [63][64]
    const float* __restrict__ rpw,   // [63][64]
    unsigned short* __restrict__ ao) // [MPAD][1024], rows b*NTOK+n
{
  __shared__ float RHs[64][33];   // [qrow][kh]  kh = key>>5
  __shared__ float RWc[64][33];   // [qrow][kw]  kw = key&31
  __shared__ __align__(16) unsigned short Ps[4][16][72];

  int qt = blockIdx.x;          // 0..16
  int bh = blockIdx.y;          // 0..127
  int tid = threadIdx.x, w = tid >> 6, lane = tid & 63, lr = lane & 15, lg = lane >> 4;
  int h = bh >> 3, b_ = bh & 7;

  const unsigned short* qbase = qb + (size_t)bh * NPAD * 64;
  const unsigned short* kbase = kb + (size_t)bh * NPAD * 64;
  const unsigned short* vbase = vt + (size_t)bh * 64 * NPAD;

  // Q A-fragments (wave w owns q-rows [w*16, w*16+16) of the tile)
  int qrow_lane = qt * 64 + w * 16 + lr;
  us8 aq[2];
  aq[0] = *reinterpret_cast<const us8*>(&qbase[(size_t)qrow_lane * 64 + lg * 8]);
  aq[1] = *reinterpret_cast<const us8*>(&qbase[(size_t)qrow_lane * 64 + 32 + lg * 8]);

  if (qt < 16){
    // RHs[qrow][kh] = dot(q_qrow, rel_pos_h[qh - kh + 31]); qh wave-uniform
    int qh = qt * 2 + (w >> 1);
    f32x4 ah[2] = {};
    f32x4 aw4[4] = {};
    #pragma unroll
    for (int ks = 0; ks < 2; ks++){
      #pragma unroll
      for (int nf = 0; nf < 2; nf++){
        int kh = nf * 16 + lr;
        const float* src = rph + (size_t)(qh - kh + 31) * 64 + ks * 32 + lg * 8;
        us8 bfh;
        #pragma unroll
        for (int j = 0; j < 8; j++) bfh[j] = f2bf(src[j]);
        ah[nf] = MFMA16(aq[ks], bfh, ah[nf]);
      }
      // RW: full 63-wide table in regs, compact on the write
      #pragma unroll
      for (int nf = 0; nf < 4; nf++){
        int t = nf * 16 + lr;
        us8 bfw;
        #pragma unroll
        for (int j = 0; j < 8; j++)
          bfw[j] = (t < 63) ? f2bf(rpw[(size_t)t * 64 + ks * 32 + lg * 8 + j]) : (unsigned short)0;
        aw4[nf] = MFMA16(aq[ks], bfw, aw4[nf]);
      }
    }
    #pragma unroll
    for (int nf = 0; nf < 2; nf++)
      #pragma unroll
      for (int reg = 0; reg < 4; reg++)
        RHs[w*16 + lg*4 + reg][nf*16 + lr] = ah[nf][reg];
    #pragma unroll
    for (int nf = 0; nf < 4; nf++)
      #pragma unroll
      for (int reg = 0; reg < 4; reg++){
        int qrow = w*16 + lg*4 + reg;
        int kw = (qrow & 31) - (nf*16 + lr) + 31;   // qw - idxw + 31
        if (kw >= 0 && kw < 32) RWc[qrow][kw] = aw4[nf][reg];
      }
    // no barrier: each wave only reads rows it wrote
  }

  float m_run[4] = {-1e30f, -1e30f, -1e30f, -1e30f};
  float l_run[4] = {0.f, 0.f, 0.f, 0.f};
  f32x4 O[4] = {};

  for (int kt = 0; kt < 17; kt++){
    // S = Q @ K^T  (per wave: 16 q-rows x 64 keys)
    f32x4 S[4] = {};
    #pragma unroll
    for (int ks = 0; ks < 2; ks++){
      #pragma unroll
      for (int nf = 0; nf < 4; nf++){
        us8 bk = *reinterpret_cast<const us8*>(
            &kbase[(size_t)(kt*64 + nf*16 + lr) * 64 + ks*32 + lg*8]);
        S[nf] = MFMA16(aq[ks], bk, S[nf]);
      }
    }
    // logits = S*scale + rel bias, mask invalid keys
    float p[4][4];
    bool grid_kt = (qt < 16) && (kt < 16);
    #pragma unroll
    for (int nf = 0; nf < 4; nf++){
      int kh_t = kt*2 + (nf >> 1);
      int kw_t = (nf & 1)*16 + lr;
      #pragma unroll
      for (int reg = 0; reg < 4; reg++){
        int key = kt*64 + nf*16 + lr;
        float s = S[nf][reg] * 0.125f;
        if (grid_kt){
          int qrow = w*16 + lg*4 + reg;
          s += RHs[qrow][kh_t] + RWc[qrow][kw_t];
        }
        if (key >= NTOK) s = -1e30f;
        p[nf][reg] = s;
      }
    }
    // online softmax per q-row (rows = regs, spread over 16 lanes)
    #pragma unroll
    for (int reg = 0; reg < 4; reg++){
      float tm = fmaxf(fmaxf(p[0][reg], p[1][reg]), fmaxf(p[2][reg], p[3][reg]));
      #pragma unroll
      for (int off = 1; off < 16; off <<= 1) tm = fmaxf(tm, __shfl_xor(tm, off));
      float mnew = fmaxf(m_run[reg], tm);
      float alpha = __expf(m_run[reg] - mnew);
      float rs = 0.f;
      #pragma unroll
      for (int nf = 0; nf < 4; nf++){
        float pe = __expf(p[nf][reg] - mnew);
        p[nf][reg] = pe;
        rs += pe;
      }
      #pragma unroll
      for (int off = 1; off < 16; off <<= 1) rs += __shfl_xor(rs, off);
      l_run[reg] = l_run[reg] * alpha + rs;
      m_run[reg] = mnew;
      #pragma unroll
      for (int nfd = 0; nfd < 4; nfd++) O[nfd][reg] *= alpha;
    }
    // P: C-layout -> A-layout via per-wave LDS (bf16)
    #pragma unroll
    for (int nf = 0; nf < 4; nf++)
      #pragma unroll
      for (int reg = 0; reg < 4; reg++)
        Ps[w][lg*4 + reg][nf*16 + lr] = f2bf(p[nf][reg]);
    us8 pa[2];
    pa[0] = *reinterpret_cast<const us8*>(&Ps[w][lr][lg*8]);
    pa[1] = *reinterpret_cast<const us8*>(&Ps[w][lr][32 + lg*8]);
    // O += P @ V  (V transposed: [d][key])
    #pragma unroll
    for (int ks = 0; ks < 2; ks++){
      #pragma unroll
      for (int nfd = 0; nfd < 4; nfd++){
        us8 bv = *reinterpret_cast<const us8*>(
            &vbase[(size_t)(nfd*16 + lr) * NPAD + kt*64 + ks*32 + lg*8]);
        O[nfd] = MFMA16(pa[ks], bv, O[nfd]);
      }
    }
  }

  // epilogue: O /= l, write [b][n][h*64+d]
  #pragma unroll
  for (int reg = 0; reg < 4; reg++){
    float inv = 1.0f / l_run[reg];
    int qrow = w*16 + lg*4 + reg;
    int qg = qt*64 + qrow;
    if (qg < NTOK){
      #pragma unroll
      for (int nfd = 0; nfd < 4; nfd++){
        int d = nfd*16 + lr;
        ao[(size_t)(b_ * NTOK + qg) * 1024 + h * 64 + d] = f2bf(O[nfd][reg] * inv);
      }
    }
  }
}

// ---------------- proj GEMM (m97 structure): out[MTOT][1024] = A * W^T + b ----------------
__global__ __launch_bounds__(256,2) void proj_gemm(
    const unsigned short* __restrict__ A,   // [MPAD][1024]
    const unsigned short* __restrict__ Bw,  // [1024][1024]
    const float* __restrict__ bias,
    float* __restrict__ out)
{
  const int K = 1024;
  __shared__ __align__(16) unsigned short As[128*32];
  __shared__ __align__(16) unsigned short Bs[128*32];
  int tid = threadIdx.x;
  int m0 = blockIdx.y * 128, n0 = blockIdx.x * 128;
  int w = tid >> 6, lane = tid & 63, lr = lane & 15, lg = lane >> 4;
  int wr = w >> 1, wc = w & 1;
  int srow = lane >> 2, scol = (lane & 3) * 8;
  f32x4 acc[4][4] = {};

  for (int k0 = 0; k0 < K; k0 += 32){
    __syncthreads();
    #pragma unroll
    for (int i = 0; i < 2; i++){
      int q = w * 2 + i;
      gl_lds16(&A [(size_t)(m0 + q*16 + srow) * K + k0 + scol], &As[q*512]);
      gl_lds16(&Bw[(size_t)(n0 + q*16 + srow) * K + k0 + scol], &Bs[q*512]);
    }
    __syncthreads();
    us8 a[4], b[4];
    #pragma unroll
    for (int mi = 0; mi < 4; mi++) a[mi] = *reinterpret_cast<const us8*>(&As[(wr*64 + mi*16 + lr)*32 + lg*8]);
    #pragma unroll
    for (int ni = 0; ni < 4; ni++) b[ni] = *reinterpret_cast<const us8*>(&Bs[(wc*64 + ni*16 + lr)*32 + lg*8]);
    #pragma unroll
    for (int mi = 0; mi < 4; mi++)
      #pragma unroll
      for (int ni = 0; ni < 4; ni++)
        acc[mi][ni] = MFMA16(a[mi], b[ni], acc[mi][ni]);
  }

  #pragma unroll
  for (int mi = 0; mi < 4; mi++){
    #pragma unroll
    for (int ni = 0; ni < 4; ni++){
      #pragma unroll
      for (int reg = 0; reg < 4; reg++){
        int m = m0 + wr*64 + mi*16 + lg*4 + reg;
        if (m >= MTOT) continue;
        int n = n0 + wc*64 + ni*16 + lr;
        out[(size_t)m * 1024 + n] = acc[mi][ni][reg] + bias[n];
      }
    }
  }
}

extern "C" void kernel_launch(void* const* d_in, const int* in_sizes, int n_in,
                              void* d_out, int out_size, void* d_ws, size_t ws_size,
                              hipStream_t stream)
{
  const float* x      = (const float*)d_in[0];
  const float* qkv_w  = (const float*)d_in[1];
  const float* qkv_b  = (const float*)d_in[2];
  const float* proj_w = (const float*)d_in[3];
  const float* proj_b = (const float*)d_in[4];
  const float* rph    = (const float*)d_in[5];
  const float* rpw    = (const float*)d_in[6];
  float* out = (float*)d_out;

  char* ws = (char*)d_ws;
  size_t off = 0;
  auto alloc = [&](size_t bytes){ char* p = ws + off; off += (bytes + 255) & ~(size_t)255; return p; };
  unsigned short* x_bf  = (unsigned short*)alloc((size_t)MPAD * 1024 * 2);
  unsigned short* qw_bf = (unsigned short*)alloc((size_t)3072 * 1024 * 2);
  unsigned short* pw_bf = (unsigned short*)alloc((size_t)1024 * 1024 * 2);
  unsigned short* qbuf  = (unsigned short*)alloc((size_t)128 * NPAD * 64 * 2);
  unsigned short* kbuf  = (unsigned short*)alloc((size_t)128 * NPAD * 64 * 2);
  unsigned short* vtbuf = (unsigned short*)alloc((size_t)128 * 64 * NPAD * 2);
  unsigned short* aout  = (unsigned short*)alloc((size_t)MPAD * 1024 * 2);
  if (off > ws_size) return;   // workspace too small: fail visibly

  int n4x = MTOT * 1024 / 4;
  cvt_f32_bf16<<<dim3((n4x + 255) / 256), 256, 0, stream>>>(x, x_bf, n4x);
  int n4q = 3072 * 1024 / 4;
  cvt_f32_bf16<<<dim3((n4q + 255) / 256), 256, 0, stream>>>(qkv_w, qw_bf, n4q);
  int n4p = 1024 * 1024 / 4;
  cvt_f32_bf16<<<dim3((n4p + 255) / 256), 256, 0, stream>>>(proj_w, pw_bf, n4p);

  int npad = 128 * (NPAD - NTOK) * 64 + 2 * (MPAD - MTOT) * 1024;
  pad_zero<<<dim3((npad + 255) / 256), 256, 0, stream>>>(qbuf, kbuf, vtbuf, x_bf, aout);

  qkv_gemm<<<dim3(24, 65), 256, 0, stream>>>(x_bf, qw_bf, qkv_b, qbuf, kbuf, vtbuf);
  attn_kernel<<<dim3(17, 128), 256, 0, stream>>>(qbuf, kbuf, vtbuf, rph, rpw, aout);
  proj_gemm<<<dim3(8, 65), 256, 0, stream>>>(aout, pw_bf, proj_b, out);
}

// Round 3
// 320.284 us; speedup vs baseline: 1.6365x; 1.6365x over previous
//
#include <hip/hip_runtime.h>

#define BATCH 8
#define NTOK 1032
#define NPAD 1152
#define MTOT (BATCH*NTOK)   // 8256
#define MPAD 8320           // 65 * 128

typedef __bf16 bf16x8 __attribute__((ext_vector_type(8)));
typedef float f32x4 __attribute__((ext_vector_type(4)));
typedef unsigned short us8 __attribute__((ext_vector_type(8)));
typedef unsigned short us4 __attribute__((ext_vector_type(4)));

__device__ __forceinline__ unsigned short f2bf(float f){
  unsigned int u = __builtin_bit_cast(unsigned int, f);
  u += 0x7fffu + ((u >> 16) & 1u);          // RNE
  return (unsigned short)(u >> 16);
}
__device__ __forceinline__ float bf2f(unsigned short u){
  return __builtin_bit_cast(float, (unsigned int)u << 16);
}

#define MFMA16(a,b,c) __builtin_amdgcn_mfma_f32_16x16x32_bf16( \
    __builtin_bit_cast(bf16x8,(a)), __builtin_bit_cast(bf16x8,(b)), (c), 0, 0, 0)

// async global->LDS, 16B per lane, dest = wave-uniform base + lane*16
__device__ __forceinline__ void gl_lds16(const unsigned short* g, unsigned short* l){
  __builtin_amdgcn_global_load_lds(
      (const __attribute__((address_space(1))) unsigned int*)g,
      (__attribute__((address_space(3))) unsigned int*)l, 16, 0, 0);
}

// ---------------- fp32 -> bf16 conversion ----------------
__global__ __launch_bounds__(256) void cvt_f32_bf16(const float* __restrict__ in,
                                                    unsigned short* __restrict__ out, int n4){
  int i = blockIdx.x * 256 + threadIdx.x;
  if (i < n4){
    float4 v = reinterpret_cast<const float4*>(in)[i];
    us4 o; o.x = f2bf(v.x); o.y = f2bf(v.y); o.z = f2bf(v.z); o.w = f2bf(v.w);
    reinterpret_cast<us4*>(out)[i] = o;
  }
}

// ---------------- zero all padded regions ----------------
__global__ __launch_bounds__(256) void pad_zero(unsigned short* __restrict__ qb,
                                                unsigned short* __restrict__ kb,
                                                unsigned short* __restrict__ vt,
                                                unsigned short* __restrict__ xb,
                                                unsigned short* __restrict__ ao){
  int i = blockIdx.x * 256 + threadIdx.x;
  const int t1 = 128 * (NPAD - NTOK) * 64;          // q/k/v pad rows
  const int t2 = t1 + (MPAD - MTOT) * 1024;         // x_bf pad rows
  const int t3 = t2 + (MPAD - MTOT) * 1024;         // aout pad rows
  if (i < t1){
    int bh = i / ((NPAD - NTOK) * 64);
    int r  = (i / 64) % (NPAD - NTOK);
    int d  = i % 64;
    int idx = (bh * NPAD + NTOK + r) * 64 + d;
    qb[idx] = 0;
    kb[idx] = 0;
    vt[(bh * 64 + d) * NPAD + NTOK + r] = 0;
  } else if (i < t2){
    xb[(size_t)MTOT * 1024 + (i - t1)] = 0;
  } else if (i < t3){
    ao[(size_t)MTOT * 1024 + (i - t2)] = 0;
  }
}

// ---------------- QKV GEMM (m97 structure): C[MPAD][3072] = A * W^T ----------------
__global__ __launch_bounds__(256,2) void qkv_gemm(
    const unsigned short* __restrict__ A,   // [MPAD][1024] bf16
    const unsigned short* __restrict__ Bw,  // [3072][1024] bf16
    const float* __restrict__ bias,         // [3072]
    unsigned short* __restrict__ qb,        // [128][NPAD][64]
    unsigned short* __restrict__ kb,        // [128][NPAD][64]
    unsigned short* __restrict__ vt)        // [128][64][NPAD]
{
  const int K = 1024;
  __shared__ __align__(16) unsigned short As[128*32];
  __shared__ __align__(16) unsigned short Bs[128*32];
  int tid = threadIdx.x;
  int m0 = blockIdx.y * 128, n0 = blockIdx.x * 128;
  int w = tid >> 6, lane = tid & 63, lr = lane & 15, lg = lane >> 4;
  int wr = w >> 1, wc = w & 1;
  int srow = lane >> 2, scol = (lane & 3) * 8;
  f32x4 acc[4][4] = {};

  for (int k0 = 0; k0 < K; k0 += 32){
    __syncthreads();
    #pragma unroll
    for (int i = 0; i < 2; i++){
      int q = w * 2 + i;                       // 8 chunks of 16 rows
      gl_lds16(&A [(size_t)(m0 + q*16 + srow) * K + k0 + scol], &As[q*512]);
      gl_lds16(&Bw[(size_t)(n0 + q*16 + srow) * K + k0 + scol], &Bs[q*512]);
    }
    __syncthreads();
    us8 a[4], b[4];
    #pragma unroll
    for (int mi = 0; mi < 4; mi++) a[mi] = *reinterpret_cast<const us8*>(&As[(wr*64 + mi*16 + lr)*32 + lg*8]);
    #pragma unroll
    for (int ni = 0; ni < 4; ni++) b[ni] = *reinterpret_cast<const us8*>(&Bs[(wc*64 + ni*16 + lr)*32 + lg*8]);
    #pragma unroll
    for (int mi = 0; mi < 4; mi++)
      #pragma unroll
      for (int ni = 0; ni < 4; ni++)
        acc[mi][ni] = MFMA16(a[mi], b[ni], acc[mi][ni]);
  }

  // epilogue: scatter into q/k [bh][n][64] and v transposed [bh][64][n]
  #pragma unroll
  for (int mi = 0; mi < 4; mi++){
    #pragma unroll
    for (int ni = 0; ni < 4; ni++){
      #pragma unroll
      for (int reg = 0; reg < 4; reg++){
        int m = m0 + wr*64 + mi*16 + lg*4 + reg;
        if (m >= MTOT) continue;
        int n = n0 + wc*64 + ni*16 + lr;
        float val = acc[mi][ni][reg] + bias[n];
        int b_ = m / NTOK, nidx = m % NTOK;
        int t = n >> 10, h = (n >> 6) & 15, d = n & 63;
        int bh = h * BATCH + b_;
        unsigned short bv = f2bf(val);
        if (t == 0)      qb[(size_t)(bh * NPAD + nidx) * 64 + d] = bv;
        else if (t == 1) kb[(size_t)(bh * NPAD + nidx) * 64 + d] = bv;
        else             vt[(size_t)(bh * 64 + d) * NPAD + nidx] = bv;
      }
    }
  }
}

// ---------------- flash attention v3: 128 q-rows/block, LDS-staged K/V, no-max softmax ----------------
__global__ __launch_bounds__(256,2) void attn_kernel(
    const unsigned short* __restrict__ qb,
    const unsigned short* __restrict__ kb,
    const unsigned short* __restrict__ vt,
    const float* __restrict__ rph,   // [63][64]
    const float* __restrict__ rpw,   // [63][64]
    unsigned short* __restrict__ ao) // [MPAD][1024], rows b*NTOK+n
{
  __shared__ __align__(16) unsigned short Ks[2][64*64];   // 16 KB, XOR-swizzled chunks
  __shared__ __align__(16) unsigned short Vs[2][64*64];   // 16 KB
  __shared__ unsigned short RHb[128][36];                 // bias_h[qrow][kh], bf16
  __shared__ unsigned short RWb[128][36];                 // bias_w[qrow][kw], bf16
  __shared__ __align__(16) unsigned short Ps[4][32*72];   // per-wave P relayout

  int qt = blockIdx.x;          // 0..8 (128 q-rows each)
  int bh = blockIdx.y;          // 0..127
  int tid = threadIdx.x, w = tid >> 6, lane = tid & 63, lr = lane & 15, lg = lane >> 4;
  int h = bh >> 3, b_ = bh & 7;

  const unsigned short* qbase = qb + (size_t)bh * NPAD * 64;
  const unsigned short* kbase = kb + (size_t)bh * NPAD * 64;
  const unsigned short* vbase = vt + (size_t)bh * 64 * NPAD;

  // ---- stage kt=0 (issued first; latency hidden under Q load + table build) ----
  #pragma unroll
  for (int t = 0; t < 2; t++){
    int i = t*256 + tid;                 // chunk 0..511 (row*8 + cc)
    int row = i >> 3, cs = (i & 7) ^ (row & 7);
    gl_lds16(&kbase[(size_t)row*64 + cs*8],   &Ks[0][(t*256 + w*64)*8]);
    gl_lds16(&vbase[(size_t)row*NPAD + cs*8], &Vs[0][(t*256 + w*64)*8]);
  }

  // ---- Q fragments: wave w owns q-rows [w*32, w*32+32), 2 frags ----
  us8 aq[2][2];
  #pragma unroll
  for (int qf = 0; qf < 2; qf++){
    int qrow = qt*128 + w*32 + qf*16 + lr;
    aq[qf][0] = *reinterpret_cast<const us8*>(&qbase[(size_t)qrow*64 + lg*8]);
    aq[qf][1] = *reinterpret_cast<const us8*>(&qbase[(size_t)qrow*64 + 32 + lg*8]);
  }

  // ---- rel-pos tables (grid q-rows only). qh = qg>>5 is wave-uniform. ----
  if (qt < 8){
    int qh = qt*4 + w;
    f32x4 ah[2][2] = {};
    f32x4 aw[2][4] = {};
    #pragma unroll
    for (int ks = 0; ks < 2; ks++){
      #pragma unroll
      for (int nf = 0; nf < 4; nf++){
        int t = nf*16 + lr;
        us8 bw_ = {};
        if (t < 63){
          const float* s = &rpw[(size_t)t*64 + ks*32 + lg*8];
          #pragma unroll
          for (int j = 0; j < 8; j++) bw_[j] = f2bf(s[j]);
        }
        #pragma unroll
        for (int qf = 0; qf < 2; qf++) aw[qf][nf] = MFMA16(aq[qf][ks], bw_, aw[qf][nf]);
        if (nf < 2){
          const float* s2 = &rph[(size_t)(qh - t + 31)*64 + ks*32 + lg*8];  // t = kh in 0..31
          us8 bh_;
          #pragma unroll
          for (int j = 0; j < 8; j++) bh_[j] = f2bf(s2[j]);
          #pragma unroll
          for (int qf = 0; qf < 2; qf++) ah[qf][nf] = MFMA16(aq[qf][ks], bh_, ah[qf][nf]);
        }
      }
    }
    #pragma unroll
    for (int qf = 0; qf < 2; qf++)
      #pragma unroll
      for (int reg = 0; reg < 4; reg++){
        int rowL = w*32 + qf*16 + lg*4 + reg;
        #pragma unroll
        for (int nf = 0; nf < 2; nf++)
          RHb[rowL][nf*16 + lr] = f2bf(ah[qf][nf][reg]);
        int qw = (qf*16 + lg*4 + reg) & 31;   // == rowL & 31
        #pragma unroll
        for (int nf = 0; nf < 4; nf++){
          int kw = qw - (nf*16 + lr) + 31;
          if (kw >= 0 && kw < 32) RWb[rowL][kw] = f2bf(aw[qf][nf][reg]);
        }
      }
  }
  __syncthreads();   // tables visible (own-wave only, but also drains stage-0)

  f32x4 O[2][4] = {};
  f32x4 lac[2] = {};
  us8 ones;
  #pragma unroll
  for (int j = 0; j < 8; j++) ones[j] = 0x3F80;   // bf16 1.0
  unsigned short* myPs = &Ps[w][0];

  for (int kt = 0; kt < 17; kt++){
    int cur = kt & 1;
    if (kt < 16){
      #pragma unroll
      for (int t = 0; t < 2; t++){
        int i = t*256 + tid;
        int row = i >> 3, cs = (i & 7) ^ (row & 7);
        gl_lds16(&kbase[(size_t)((kt+1)*64 + row)*64 + cs*8],     &Ks[cur^1][(t*256 + w*64)*8]);
        gl_lds16(&vbase[(size_t)row*NPAD + (kt+1)*64 + cs*8],     &Vs[cur^1][(t*256 + w*64)*8]);
      }
    }

    // ---- QK^T: S[qf][nf], K-frags from swizzled LDS ----
    f32x4 S[2][4] = {};
    __builtin_amdgcn_s_setprio(1);
    #pragma unroll
    for (int ks = 0; ks < 2; ks++)
      #pragma unroll
      for (int nf = 0; nf < 4; nf++){
        us8 bk = *reinterpret_cast<const us8*>(
            &Ks[cur][(nf*16 + lr)*64 + (((ks*4 + lg) ^ (lr & 7)) * 8)]);
        S[0][nf] = MFMA16(aq[0][ks], bk, S[0][nf]);
        S[1][nf] = MFMA16(aq[1][ks], bk, S[1][nf]);
      }
    __builtin_amdgcn_s_setprio(0);

    // ---- logits -> P = exp(s - 4), no running max (logits bounded ~|3|) ----
    bool grid_kt = (qt < 8) && (kt < 16);
    #pragma unroll
    for (int qf = 0; qf < 2; qf++)
      #pragma unroll
      for (int nf = 0; nf < 4; nf++){
        int kh_t = kt*2 + (nf >> 1);
        int kwv  = (nf & 1)*16 + lr;
        #pragma unroll
        for (int reg = 0; reg < 4; reg++){
          int rowL = w*32 + qf*16 + lg*4 + reg;
          float s = S[qf][nf][reg] * 0.125f - 4.0f;
          if (grid_kt) s += bf2f(RHb[rowL][kh_t]) + bf2f(RWb[rowL][kwv]);
          int key = kt*64 + nf*16 + lr;
          if (key >= NTOK) s = -1e30f;
          float p = __expf(s);
          // truncation to bf16: consistent in PV numerator and l denominator
          myPs[(qf*16 + lg*4 + reg)*72 + nf*16 + lr] =
              (unsigned short)(__builtin_bit_cast(unsigned int, p) >> 16);
        }
      }

    // ---- P @ V and row-sum l via ones-MFMA ----
    __builtin_amdgcn_s_setprio(1);
    #pragma unroll
    for (int qf = 0; qf < 2; qf++){
      #pragma unroll
      for (int ks = 0; ks < 2; ks++){
        us8 pa = *reinterpret_cast<const us8*>(&myPs[(qf*16 + lr)*72 + ks*32 + lg*8]);
        lac[qf] = MFMA16(pa, ones, lac[qf]);
        #pragma unroll
        for (int nfd = 0; nfd < 4; nfd++){
          us8 bv = *reinterpret_cast<const us8*>(
              &Vs[cur][(nfd*16 + lr)*64 + (((ks*4 + lg) ^ (lr & 7)) * 8)]);
          O[qf][nfd] = MFMA16(pa, bv, O[qf][nfd]);
        }
      }
    }
    __builtin_amdgcn_s_setprio(0);
    __syncthreads();   // drains next-tile stage; protects dbuf reuse
  }

  // ---- epilogue: O /= l, write [b][n][h*64+d] ----
  #pragma unroll
  for (int qf = 0; qf < 2; qf++)
    #pragma unroll
    for (int reg = 0; reg < 4; reg++){
      int qg = qt*128 + w*32 + qf*16 + lg*4 + reg;
      if (qg < NTOK){
        float inv = 1.0f / lac[qf][reg];
        #pragma unroll
        for (int nfd = 0; nfd < 4; nfd++)
          ao[(size_t)(b_ * NTOK + qg) * 1024 + h*64 + nfd*16 + lr] = f2bf(O[qf][nfd][reg] * inv);
      }
    }
}

// ---------------- proj GEMM (m97 structure): out[MTOT][1024] = A * W^T + b ----------------
__global__ __launch_bounds__(256,2) void proj_gemm(
    const unsigned short* __restrict__ A,   // [MPAD][1024]
    const unsigned short* __restrict__ Bw,  // [1024][1024]
    const float* __restrict__ bias,
    float* __restrict__ out)
{
  const int K = 1024;
  __shared__ __align__(16) unsigned short As[128*32];
  __shared__ __align__(16) unsigned short Bs[128*32];
  int tid = threadIdx.x;
  int m0 = blockIdx.y * 128, n0 = blockIdx.x * 128;
  int w = tid >> 6, lane = tid & 63, lr = lane & 15, lg = lane >> 4;
  int wr = w >> 1, wc = w & 1;
  int srow = lane >> 2, scol = (lane & 3) * 8;
  f32x4 acc[4][4] = {};

  for (int k0 = 0; k0 < K; k0 += 32){
    __syncthreads();
    #pragma unroll
    for (int i = 0; i < 2; i++){
      int q = w * 2 + i;
      gl_lds16(&A [(size_t)(m0 + q*16 + srow) * K + k0 + scol], &As[q*512]);
      gl_lds16(&Bw[(size_t)(n0 + q*16 + srow) * K + k0 + scol], &Bs[q*512]);
    }
    __syncthreads();
    us8 a[4], b[4];
    #pragma unroll
    for (int mi = 0; mi < 4; mi++) a[mi] = *reinterpret_cast<const us8*>(&As[(wr*64 + mi*16 + lr)*32 + lg*8]);
    #pragma unroll
    for (int ni = 0; ni < 4; ni++) b[ni] = *reinterpret_cast<const us8*>(&Bs[(wc*64 + ni*16 + lr)*32 + lg*8]);
    #pragma unroll
    for (int mi = 0; mi < 4; mi++)
      #pragma unroll
      for (int ni = 0; ni < 4; ni++)
        acc[mi][ni] = MFMA16(a[mi], b[ni], acc[mi][ni]);
  }

  #pragma unroll
  for (int mi = 0; mi < 4; mi++){
    #pragma unroll
    for (int ni = 0; ni < 4; ni++){
      #pragma unroll
      for (int reg = 0; reg < 4; reg++){
        int m = m0 + wr*64 + mi*16 + lg*4 + reg;
        if (m >= MTOT) continue;
        int n = n0 + wc*64 + ni*16 + lr;
        out[(size_t)m * 1024 + n] = acc[mi][ni][reg] + bias[n];
      }
    }
  }
}

extern "C" void kernel_launch(void* const* d_in, const int* in_sizes, int n_in,
                              void* d_out, int out_size, void* d_ws, size_t ws_size,
                              hipStream_t stream)
{
  const float* x      = (const float*)d_in[0];
  const float* qkv_w  = (const float*)d_in[1];
  const float* qkv_b  = (const float*)d_in[2];
  const float* proj_w = (const float*)d_in[3];
  const float* proj_b = (const float*)d_in[4];
  const float* rph    = (const float*)d_in[5];
  const float* rpw    = (const float*)d_in[6];
  float* out = (float*)d_out;

  char* ws = (char*)d_ws;
  size_t off = 0;
  auto alloc = [&](size_t bytes){ char* p = ws + off; off += (bytes + 255) & ~(size_t)255; return p; };
  unsigned short* x_bf  = (unsigned short*)alloc((size_t)MPAD * 1024 * 2);
  unsigned short* qw_bf = (unsigned short*)alloc((size_t)3072 * 1024 * 2);
  unsigned short* pw_bf = (unsigned short*)alloc((size_t)1024 * 1024 * 2);
  unsigned short* qbuf  = (unsigned short*)alloc((size_t)128 * NPAD * 64 * 2);
  unsigned short* kbuf  = (unsigned short*)alloc((size_t)128 * NPAD * 64 * 2);
  unsigned short* vtbuf = (unsigned short*)alloc((size_t)128 * 64 * NPAD * 2);
  unsigned short* aout  = (unsigned short*)alloc((size_t)MPAD * 1024 * 2);
  if (off > ws_size) return;   // workspace too small: fail visibly

  int n4x = MTOT * 1024 / 4;
  cvt_f32_bf16<<<dim3((n4x + 255) / 256), 256, 0, stream>>>(x, x_bf, n4x);
  int n4q = 3072 * 1024 / 4;
  cvt_f32_bf16<<<dim3((n4q + 255) / 256), 256, 0, stream>>>(qkv_w, qw_bf, n4q);
  int n4p = 1024 * 1024 / 4;
  cvt_f32_bf16<<<dim3((n4p + 255) / 256), 256, 0, stream>>>(proj_w, pw_bf, n4p);

  int npad = 128 * (NPAD - NTOK) * 64 + 2 * (MPAD - MTOT) * 1024;
  pad_zero<<<dim3((npad + 255) / 256), 256, 0, stream>>>(qbuf, kbuf, vtbuf, x_bf, aout);

  qkv_gemm<<<dim3(24, 65), 256, 0, stream>>>(x_bf, qw_bf, qkv_b, qbuf, kbuf, vtbuf);
  attn_kernel<<<dim3(9, 128), 256, 0, stream>>>(qbuf, kbuf, vtbuf, rph, rpw, aout);
  proj_gemm<<<dim3(8, 65), 256, 0, stream>>>(aout, pw_bf, proj_b, out);
}

// Round 4
// 303.579 us; speedup vs baseline: 1.7266x; 1.0550x over previous
//
#include <hip/hip_runtime.h>

#define BATCH 8
#define NTOK 1032
#define NPAD 1152
#define MTOT (BATCH*NTOK)   // 8256
#define MPAD 8320           // 65 * 128

typedef __bf16 bf16x8 __attribute__((ext_vector_type(8)));
typedef float f32x4 __attribute__((ext_vector_type(4)));
typedef unsigned short us8 __attribute__((ext_vector_type(8)));
typedef unsigned short us4 __attribute__((ext_vector_type(4)));

__device__ __forceinline__ unsigned short f2bf(float f){
  unsigned int u = __builtin_bit_cast(unsigned int, f);
  u += 0x7fffu + ((u >> 16) & 1u);          // RNE
  return (unsigned short)(u >> 16);
}
__device__ __forceinline__ float bf2f(unsigned short u){
  return __builtin_bit_cast(float, (unsigned int)u << 16);
}

#define MFMA16(a,b,c) __builtin_amdgcn_mfma_f32_16x16x32_bf16( \
    __builtin_bit_cast(bf16x8,(a)), __builtin_bit_cast(bf16x8,(b)), (c), 0, 0, 0)

// async global->LDS, 16B per lane, dest = wave-uniform base + lane*16
__device__ __forceinline__ void gl_lds16(const unsigned short* g, unsigned short* l){
  __builtin_amdgcn_global_load_lds(
      (const __attribute__((address_space(1))) unsigned int*)g,
      (__attribute__((address_space(3))) unsigned int*)l, 16, 0, 0);
}

// ---------------- fp32 -> bf16 conversion ----------------
__global__ __launch_bounds__(256) void cvt_f32_bf16(const float* __restrict__ in,
                                                    unsigned short* __restrict__ out, int n4){
  int i = blockIdx.x * 256 + threadIdx.x;
  if (i < n4){
    float4 v = reinterpret_cast<const float4*>(in)[i];
    us4 o; o.x = f2bf(v.x); o.y = f2bf(v.y); o.z = f2bf(v.z); o.w = f2bf(v.w);
    reinterpret_cast<us4*>(out)[i] = o;
  }
}

// ---------------- zero all padded regions ----------------
__global__ __launch_bounds__(256) void pad_zero(unsigned short* __restrict__ qb,
                                                unsigned short* __restrict__ kb,
                                                unsigned short* __restrict__ vt,
                                                unsigned short* __restrict__ xb,
                                                unsigned short* __restrict__ ao){
  int i = blockIdx.x * 256 + threadIdx.x;
  const int t1 = 128 * (NPAD - NTOK) * 64;          // q/k/v pad rows
  const int t2 = t1 + (MPAD - MTOT) * 1024;         // x_bf pad rows
  const int t3 = t2 + (MPAD - MTOT) * 1024;         // aout pad rows
  if (i < t1){
    int bh = i / ((NPAD - NTOK) * 64);
    int r  = (i / 64) % (NPAD - NTOK);
    int d  = i % 64;
    int idx = (bh * NPAD + NTOK + r) * 64 + d;
    qb[idx] = 0;
    kb[idx] = 0;
    vt[(bh * 64 + d) * NPAD + NTOK + r] = 0;
  } else if (i < t2){
    xb[(size_t)MTOT * 1024 + (i - t1)] = 0;
  } else if (i < t3){
    ao[(size_t)MTOT * 1024 + (i - t2)] = 0;
  }
}

// ---------------- QKV GEMM (m97 structure + XCD swizzle): C[MPAD][3072] = A * W^T ----------------
__global__ __launch_bounds__(256,2) void qkv_gemm(
    const unsigned short* __restrict__ A,   // [MPAD][1024] bf16
    const unsigned short* __restrict__ Bw,  // [3072][1024] bf16
    const float* __restrict__ bias,         // [3072]
    unsigned short* __restrict__ qb,        // [128][NPAD][64]
    unsigned short* __restrict__ kb,        // [128][NPAD][64]
    unsigned short* __restrict__ vt)        // [128][64][NPAD]
{
  const int K = 1024;
  __shared__ __align__(16) unsigned short As[128*32];
  __shared__ __align__(16) unsigned short Bs[128*32];
  int tid = threadIdx.x;
  // XCD swizzle: 1560 blocks = 8 XCDs x 195; m-major chunks per XCD (A-panel L2 reuse)
  int id = blockIdx.x;
  int work = (id & 7) * 195 + (id >> 3);
  int m0 = (work / 24) * 128, n0 = (work % 24) * 128;
  int w = tid >> 6, lane = tid & 63, lr = lane & 15, lg = lane >> 4;
  int wr = w >> 1, wc = w & 1;
  int srow = lane >> 2, scol = (lane & 3) * 8;
  f32x4 acc[4][4] = {};

  for (int k0 = 0; k0 < K; k0 += 32){
    __syncthreads();
    #pragma unroll
    for (int i = 0; i < 2; i++){
      int q = w * 2 + i;                       // 8 chunks of 16 rows
      gl_lds16(&A [(size_t)(m0 + q*16 + srow) * K + k0 + scol], &As[q*512]);
      gl_lds16(&Bw[(size_t)(n0 + q*16 + srow) * K + k0 + scol], &Bs[q*512]);
    }
    __syncthreads();
    us8 a[4], b[4];
    #pragma unroll
    for (int mi = 0; mi < 4; mi++) a[mi] = *reinterpret_cast<const us8*>(&As[(wr*64 + mi*16 + lr)*32 + lg*8]);
    #pragma unroll
    for (int ni = 0; ni < 4; ni++) b[ni] = *reinterpret_cast<const us8*>(&Bs[(wc*64 + ni*16 + lr)*32 + lg*8]);
    #pragma unroll
    for (int mi = 0; mi < 4; mi++)
      #pragma unroll
      for (int ni = 0; ni < 4; ni++)
        acc[mi][ni] = MFMA16(a[mi], b[ni], acc[mi][ni]);
  }

  // epilogue: scatter into q/k [bh][n][64] and v transposed [bh][64][n]
  #pragma unroll
  for (int mi = 0; mi < 4; mi++){
    #pragma unroll
    for (int ni = 0; ni < 4; ni++){
      #pragma unroll
      for (int reg = 0; reg < 4; reg++){
        int m = m0 + wr*64 + mi*16 + lg*4 + reg;
        if (m >= MTOT) continue;
        int n = n0 + wc*64 + ni*16 + lr;
        float val = acc[mi][ni][reg] + bias[n];
        int b_ = m / NTOK, nidx = m % NTOK;
        int t = n >> 10, h = (n >> 6) & 15, d = n & 63;
        int bh = h * BATCH + b_;
        unsigned short bv = f2bf(val);
        if (t == 0)      qb[(size_t)(bh * NPAD + nidx) * 64 + d] = bv;
        else if (t == 1) kb[(size_t)(bh * NPAD + nidx) * 64 + d] = bv;
        else             vt[(size_t)(bh * 64 + d) * NPAD + nidx] = bv;
      }
    }
  }
}

// ---------------- flash attention v4: v3 + XCD-clustered K/V reuse ----------------
__global__ __launch_bounds__(256,2) void attn_kernel(
    const unsigned short* __restrict__ qb,
    const unsigned short* __restrict__ kb,
    const unsigned short* __restrict__ vt,
    const float* __restrict__ rph,   // [63][64]
    const float* __restrict__ rpw,   // [63][64]
    unsigned short* __restrict__ ao) // [MPAD][1024], rows b*NTOK+n
{
  __shared__ __align__(16) unsigned short Ks[2][64*64];   // 16 KB, XOR-swizzled chunks
  __shared__ __align__(16) unsigned short Vs[2][64*64];   // 16 KB
  __shared__ unsigned short RHb[128][36];                 // bias_h[qrow][kh], bf16
  __shared__ unsigned short RWb[128][36];                 // bias_w[qrow][kw], bf16
  __shared__ __align__(16) unsigned short Ps[4][32*72];   // per-wave P relayout

  // XCD swizzle: 1152 blocks = 8 XCDs x 144; bh-major per XCD so all 9 q-tiles
  // of a bh share one XCD's L2 (K/V become L2-resident)
  int id = blockIdx.x;
  int work = (id & 7) * 144 + (id >> 3);
  int bh = work / 9;            // 0..127
  int qt = work % 9;            // 0..8 (128 q-rows each)
  int tid = threadIdx.x, w = tid >> 6, lane = tid & 63, lr = lane & 15, lg = lane >> 4;
  int h = bh >> 3, b_ = bh & 7;

  const unsigned short* qbase = qb + (size_t)bh * NPAD * 64;
  const unsigned short* kbase = kb + (size_t)bh * NPAD * 64;
  const unsigned short* vbase = vt + (size_t)bh * 64 * NPAD;

  // ---- stage kt=0 (issued first; latency hidden under Q load + table build) ----
  #pragma unroll
  for (int t = 0; t < 2; t++){
    int i = t*256 + tid;                 // chunk 0..511 (row*8 + cc)
    int row = i >> 3, cs = (i & 7) ^ (row & 7);
    gl_lds16(&kbase[(size_t)row*64 + cs*8],   &Ks[0][(t*256 + w*64)*8]);
    gl_lds16(&vbase[(size_t)row*NPAD + cs*8], &Vs[0][(t*256 + w*64)*8]);
  }

  // ---- Q fragments: wave w owns q-rows [w*32, w*32+32), 2 frags ----
  us8 aq[2][2];
  #pragma unroll
  for (int qf = 0; qf < 2; qf++){
    int qrow = qt*128 + w*32 + qf*16 + lr;
    aq[qf][0] = *reinterpret_cast<const us8*>(&qbase[(size_t)qrow*64 + lg*8]);
    aq[qf][1] = *reinterpret_cast<const us8*>(&qbase[(size_t)qrow*64 + 32 + lg*8]);
  }

  // ---- rel-pos tables (grid q-rows only). qh = qg>>5 is wave-uniform. ----
  if (qt < 8){
    int qh = qt*4 + w;
    f32x4 ah[2][2] = {};
    f32x4 aw[2][4] = {};
    #pragma unroll
    for (int ks = 0; ks < 2; ks++){
      #pragma unroll
      for (int nf = 0; nf < 4; nf++){
        int t = nf*16 + lr;
        us8 bw_ = {};
        if (t < 63){
          const float* s = &rpw[(size_t)t*64 + ks*32 + lg*8];
          #pragma unroll
          for (int j = 0; j < 8; j++) bw_[j] = f2bf(s[j]);
        }
        #pragma unroll
        for (int qf = 0; qf < 2; qf++) aw[qf][nf] = MFMA16(aq[qf][ks], bw_, aw[qf][nf]);
        if (nf < 2){
          const float* s2 = &rph[(size_t)(qh - t + 31)*64 + ks*32 + lg*8];  // t = kh in 0..31
          us8 bh_;
          #pragma unroll
          for (int j = 0; j < 8; j++) bh_[j] = f2bf(s2[j]);
          #pragma unroll
          for (int qf = 0; qf < 2; qf++) ah[qf][nf] = MFMA16(aq[qf][ks], bh_, ah[qf][nf]);
        }
      }
    }
    #pragma unroll
    for (int qf = 0; qf < 2; qf++)
      #pragma unroll
      for (int reg = 0; reg < 4; reg++){
        int rowL = w*32 + qf*16 + lg*4 + reg;
        #pragma unroll
        for (int nf = 0; nf < 2; nf++)
          RHb[rowL][nf*16 + lr] = f2bf(ah[qf][nf][reg]);
        int qw = (qf*16 + lg*4 + reg) & 31;   // == rowL & 31
        #pragma unroll
        for (int nf = 0; nf < 4; nf++){
          int kw = qw - (nf*16 + lr) + 31;
          if (kw >= 0 && kw < 32) RWb[rowL][kw] = f2bf(aw[qf][nf][reg]);
        }
      }
  }
  __syncthreads();   // tables visible (own-wave only, but also drains stage-0)

  f32x4 O[2][4] = {};
  f32x4 lac[2] = {};
  us8 ones;
  #pragma unroll
  for (int j = 0; j < 8; j++) ones[j] = 0x3F80;   // bf16 1.0
  unsigned short* myPs = &Ps[w][0];

  for (int kt = 0; kt < 17; kt++){
    int cur = kt & 1;
    if (kt < 16){
      #pragma unroll
      for (int t = 0; t < 2; t++){
        int i = t*256 + tid;
        int row = i >> 3, cs = (i & 7) ^ (row & 7);
        gl_lds16(&kbase[(size_t)((kt+1)*64 + row)*64 + cs*8],     &Ks[cur^1][(t*256 + w*64)*8]);
        gl_lds16(&vbase[(size_t)row*NPAD + (kt+1)*64 + cs*8],     &Vs[cur^1][(t*256 + w*64)*8]);
      }
    }

    // ---- QK^T: S[qf][nf], K-frags from swizzled LDS ----
    f32x4 S[2][4] = {};
    __builtin_amdgcn_s_setprio(1);
    #pragma unroll
    for (int ks = 0; ks < 2; ks++)
      #pragma unroll
      for (int nf = 0; nf < 4; nf++){
        us8 bk = *reinterpret_cast<const us8*>(
            &Ks[cur][(nf*16 + lr)*64 + (((ks*4 + lg) ^ (lr & 7)) * 8)]);
        S[0][nf] = MFMA16(aq[0][ks], bk, S[0][nf]);
        S[1][nf] = MFMA16(aq[1][ks], bk, S[1][nf]);
      }
    __builtin_amdgcn_s_setprio(0);

    // ---- logits -> P = exp(s - 4), no running max (logits bounded ~|3|) ----
    bool grid_kt = (qt < 8) && (kt < 16);
    #pragma unroll
    for (int qf = 0; qf < 2; qf++)
      #pragma unroll
      for (int nf = 0; nf < 4; nf++){
        int kh_t = kt*2 + (nf >> 1);
        int kwv  = (nf & 1)*16 + lr;
        #pragma unroll
        for (int reg = 0; reg < 4; reg++){
          int rowL = w*32 + qf*16 + lg*4 + reg;
          float s = S[qf][nf][reg] * 0.125f - 4.0f;
          if (grid_kt) s += bf2f(RHb[rowL][kh_t]) + bf2f(RWb[rowL][kwv]);
          int key = kt*64 + nf*16 + lr;
          if (key >= NTOK) s = -1e30f;
          float p = __expf(s);
          // truncation to bf16: consistent in PV numerator and l denominator
          myPs[(qf*16 + lg*4 + reg)*72 + nf*16 + lr] =
              (unsigned short)(__builtin_bit_cast(unsigned int, p) >> 16);
        }
      }

    // ---- P @ V and row-sum l via ones-MFMA ----
    __builtin_amdgcn_s_setprio(1);
    #pragma unroll
    for (int qf = 0; qf < 2; qf++){
      #pragma unroll
      for (int ks = 0; ks < 2; ks++){
        us8 pa = *reinterpret_cast<const us8*>(&myPs[(qf*16 + lr)*72 + ks*32 + lg*8]);
        lac[qf] = MFMA16(pa, ones, lac[qf]);
        #pragma unroll
        for (int nfd = 0; nfd < 4; nfd++){
          us8 bv = *reinterpret_cast<const us8*>(
              &Vs[cur][(nfd*16 + lr)*64 + (((ks*4 + lg) ^ (lr & 7)) * 8)]);
          O[qf][nfd] = MFMA16(pa, bv, O[qf][nfd]);
        }
      }
    }
    __builtin_amdgcn_s_setprio(0);
    __syncthreads();   // drains next-tile stage; protects dbuf reuse
  }

  // ---- epilogue: O /= l, write [b][n][h*64+d] ----
  #pragma unroll
  for (int qf = 0; qf < 2; qf++)
    #pragma unroll
    for (int reg = 0; reg < 4; reg++){
      int qg = qt*128 + w*32 + qf*16 + lg*4 + reg;
      if (qg < NTOK){
        float inv = 1.0f / lac[qf][reg];
        #pragma unroll
        for (int nfd = 0; nfd < 4; nfd++)
          ao[(size_t)(b_ * NTOK + qg) * 1024 + h*64 + nfd*16 + lr] = f2bf(O[qf][nfd][reg] * inv);
      }
    }
}

// ---------------- proj GEMM (m97 structure + XCD swizzle): out[MTOT][1024] = A * W^T + b ----------------
__global__ __launch_bounds__(256,2) void proj_gemm(
    const unsigned short* __restrict__ A,   // [MPAD][1024]
    const unsigned short* __restrict__ Bw,  // [1024][1024]
    const float* __restrict__ bias,
    float* __restrict__ out)
{
  const int K = 1024;
  __shared__ __align__(16) unsigned short As[128*32];
  __shared__ __align__(16) unsigned short Bs[128*32];
  int tid = threadIdx.x;
  // XCD swizzle: 520 blocks = 8 XCDs x 65; m-major chunks per XCD
  int id = blockIdx.x;
  int work = (id & 7) * 65 + (id >> 3);
  int m0 = (work / 8) * 128, n0 = (work % 8) * 128;
  int w = tid >> 6, lane = tid & 63, lr = lane & 15, lg = lane >> 4;
  int wr = w >> 1, wc = w & 1;
  int srow = lane >> 2, scol = (lane & 3) * 8;
  f32x4 acc[4][4] = {};

  for (int k0 = 0; k0 < K; k0 += 32){
    __syncthreads();
    #pragma unroll
    for (int i = 0; i < 2; i++){
      int q = w * 2 + i;
      gl_lds16(&A [(size_t)(m0 + q*16 + srow) * K + k0 + scol], &As[q*512]);
      gl_lds16(&Bw[(size_t)(n0 + q*16 + srow) * K + k0 + scol], &Bs[q*512]);
    }
    __syncthreads();
    us8 a[4], b[4];
    #pragma unroll
    for (int mi = 0; mi < 4; mi++) a[mi] = *reinterpret_cast<const us8*>(&As[(wr*64 + mi*16 + lr)*32 + lg*8]);
    #pragma unroll
    for (int ni = 0; ni < 4; ni++) b[ni] = *reinterpret_cast<const us8*>(&Bs[(wc*64 + ni*16 + lr)*32 + lg*8]);
    #pragma unroll
    for (int mi = 0; mi < 4; mi++)
      #pragma unroll
      for (int ni = 0; ni < 4; ni++)
        acc[mi][ni] = MFMA16(a[mi], b[ni], acc[mi][ni]);
  }

  #pragma unroll
  for (int mi = 0; mi < 4; mi++){
    #pragma unroll
    for (int ni = 0; ni < 4; ni++){
      #pragma unroll
      for (int reg = 0; reg < 4; reg++){
        int m = m0 + wr*64 + mi*16 + lg*4 + reg;
        if (m >= MTOT) continue;
        int n = n0 + wc*64 + ni*16 + lr;
        out[(size_t)m * 1024 + n] = acc[mi][ni][reg] + bias[n];
      }
    }
  }
}

extern "C" void kernel_launch(void* const* d_in, const int* in_sizes, int n_in,
                              void* d_out, int out_size, void* d_ws, size_t ws_size,
                              hipStream_t stream)
{
  const float* x      = (const float*)d_in[0];
  const float* qkv_w  = (const float*)d_in[1];
  const float* qkv_b  = (const float*)d_in[2];
  const float* proj_w = (const float*)d_in[3];
  const float* proj_b = (const float*)d_in[4];
  const float* rph    = (const float*)d_in[5];
  const float* rpw    = (const float*)d_in[6];
  float* out = (float*)d_out;

  char* ws = (char*)d_ws;
  size_t off = 0;
  auto alloc = [&](size_t bytes){ char* p = ws + off; off += (bytes + 255) & ~(size_t)255; return p; };
  unsigned short* x_bf  = (unsigned short*)alloc((size_t)MPAD * 1024 * 2);
  unsigned short* qw_bf = (unsigned short*)alloc((size_t)3072 * 1024 * 2);
  unsigned short* pw_bf = (unsigned short*)alloc((size_t)1024 * 1024 * 2);
  unsigned short* qbuf  = (unsigned short*)alloc((size_t)128 * NPAD * 64 * 2);
  unsigned short* kbuf  = (unsigned short*)alloc((size_t)128 * NPAD * 64 * 2);
  unsigned short* vtbuf = (unsigned short*)alloc((size_t)128 * 64 * NPAD * 2);
  unsigned short* aout  = (unsigned short*)alloc((size_t)MPAD * 1024 * 2);
  if (off > ws_size) return;   // workspace too small: fail visibly

  int n4x = MTOT * 1024 / 4;
  cvt_f32_bf16<<<dim3((n4x + 255) / 256), 256, 0, stream>>>(x, x_bf, n4x);
  int n4q = 3072 * 1024 / 4;
  cvt_f32_bf16<<<dim3((n4q + 255) / 256), 256, 0, stream>>>(qkv_w, qw_bf, n4q);
  int n4p = 1024 * 1024 / 4;
  cvt_f32_bf16<<<dim3((n4p + 255) / 256), 256, 0, stream>>>(proj_w, pw_bf, n4p);

  int npad = 128 * (NPAD - NTOK) * 64 + 2 * (MPAD - MTOT) * 1024;
  pad_zero<<<dim3((npad + 255) / 256), 256, 0, stream>>>(qbuf, kbuf, vtbuf, x_bf, aout);

  qkv_gemm<<<dim3(1560), 256, 0, stream>>>(x_bf, qw_bf, qkv_b, qbuf, kbuf, vtbuf);
  attn_kernel<<<dim3(1152), 256, 0, stream>>>(qbuf, kbuf, vtbuf, rph, rpw, aout);
  proj_gemm<<<dim3(520), 256, 0, stream>>>(aout, pw_bf, proj_b, out);
}

// Round 5
// 241.054 us; speedup vs baseline: 2.1744x; 1.2594x over previous
//
#include <hip/hip_runtime.h>

#define BATCH 8
#define NTOK 1032
#define NPAD 1152
#define MTOT (BATCH*NTOK)   // 8256
#define MPAD 8320           // 65 * 128

#define SCALE_Q 0.18033688011112042f   // 0.125 * log2(e)
#define C2      5.770780163555854f     // 4 * log2(e)

typedef __bf16 bf16x8 __attribute__((ext_vector_type(8)));
typedef float f32x4 __attribute__((ext_vector_type(4)));
typedef unsigned short us8 __attribute__((ext_vector_type(8)));
typedef unsigned short us4 __attribute__((ext_vector_type(4)));
typedef short s4 __attribute__((ext_vector_type(4)));

__device__ __forceinline__ unsigned short f2bf(float f){
  unsigned int u = __builtin_bit_cast(unsigned int, f);
  u += 0x7fffu + ((u >> 16) & 1u);          // RNE
  return (unsigned short)(u >> 16);
}
__device__ __forceinline__ float bf2f(unsigned short u){
  return __builtin_bit_cast(float, (unsigned int)u << 16);
}

#define MFMA16(a,b,c) __builtin_amdgcn_mfma_f32_16x16x32_bf16( \
    __builtin_bit_cast(bf16x8,(a)), __builtin_bit_cast(bf16x8,(b)), (c), 0, 0, 0)
// K=16 variant: A/B are 4 bf16 (2 VGPR)
#define MFMAH(a,b,c) __builtin_amdgcn_mfma_f32_16x16x16bf16_1k( \
    __builtin_bit_cast(s4,(a)), __builtin_bit_cast(s4,(b)), (c), 0, 0, 0)

// async global->LDS, 16B per lane, dest = wave-uniform base + lane*16
__device__ __forceinline__ void gl_lds16(const unsigned short* g, unsigned short* l){
  __builtin_amdgcn_global_load_lds(
      (const __attribute__((address_space(1))) unsigned int*)g,
      (__attribute__((address_space(3))) unsigned int*)l, 16, 0, 0);
}

// ---------------- fp32 -> bf16 conversion ----------------
__global__ __launch_bounds__(256) void cvt_f32_bf16(const float* __restrict__ in,
                                                    unsigned short* __restrict__ out, int n4){
  int i = blockIdx.x * 256 + threadIdx.x;
  if (i < n4){
    float4 v = reinterpret_cast<const float4*>(in)[i];
    us4 o; o.x = f2bf(v.x); o.y = f2bf(v.y); o.z = f2bf(v.z); o.w = f2bf(v.w);
    reinterpret_cast<us4*>(out)[i] = o;
  }
}

// ---------------- zero all padded regions ----------------
__global__ __launch_bounds__(256) void pad_zero(unsigned short* __restrict__ qb,
                                                unsigned short* __restrict__ kb,
                                                unsigned short* __restrict__ vt,
                                                unsigned short* __restrict__ xb,
                                                unsigned short* __restrict__ ao){
  int i = blockIdx.x * 256 + threadIdx.x;
  const int t1 = 128 * (NPAD - NTOK) * 64;          // q/k/v pad rows
  const int t2 = t1 + (MPAD - MTOT) * 1024;         // x_bf pad rows
  const int t3 = t2 + (MPAD - MTOT) * 1024;         // aout pad rows
  if (i < t1){
    int bh = i / ((NPAD - NTOK) * 64);
    int r  = (i / 64) % (NPAD - NTOK);
    int d  = i % 64;
    int idx = (bh * NPAD + NTOK + r) * 64 + d;
    qb[idx] = 0;
    kb[idx] = 0;
    vt[(bh * 64 + d) * NPAD + NTOK + r] = 0;
  } else if (i < t2){
    xb[(size_t)MTOT * 1024 + (i - t1)] = 0;
  } else if (i < t3){
    ao[(size_t)MTOT * 1024 + (i - t2)] = 0;
  }
}

// ---------------- QKV GEMM (m97 structure + XCD swizzle): C[MPAD][3072] = A * W^T ----------------
__global__ __launch_bounds__(256,2) void qkv_gemm(
    const unsigned short* __restrict__ A,   // [MPAD][1024] bf16
    const unsigned short* __restrict__ Bw,  // [3072][1024] bf16
    const float* __restrict__ bias,         // [3072]
    unsigned short* __restrict__ qb,        // [128][NPAD][64]  (q pre-scaled by SCALE_Q)
    unsigned short* __restrict__ kb,        // [128][NPAD][64]
    unsigned short* __restrict__ vt)        // [128][64][NPAD]
{
  const int K = 1024;
  __shared__ __align__(16) unsigned short As[128*32];
  __shared__ __align__(16) unsigned short Bs[128*32];
  int tid = threadIdx.x;
  int id = blockIdx.x;
  int work = (id & 7) * 195 + (id >> 3);
  int m0 = (work / 24) * 128, n0 = (work % 24) * 128;
  int w = tid >> 6, lane = tid & 63, lr = lane & 15, lg = lane >> 4;
  int wr = w >> 1, wc = w & 1;
  int srow = lane >> 2, scol = (lane & 3) * 8;
  f32x4 acc[4][4] = {};

  for (int k0 = 0; k0 < K; k0 += 32){
    __syncthreads();
    #pragma unroll
    for (int i = 0; i < 2; i++){
      int q = w * 2 + i;
      gl_lds16(&A [(size_t)(m0 + q*16 + srow) * K + k0 + scol], &As[q*512]);
      gl_lds16(&Bw[(size_t)(n0 + q*16 + srow) * K + k0 + scol], &Bs[q*512]);
    }
    __syncthreads();
    us8 a[4], b[4];
    #pragma unroll
    for (int mi = 0; mi < 4; mi++) a[mi] = *reinterpret_cast<const us8*>(&As[(wr*64 + mi*16 + lr)*32 + lg*8]);
    #pragma unroll
    for (int ni = 0; ni < 4; ni++) b[ni] = *reinterpret_cast<const us8*>(&Bs[(wc*64 + ni*16 + lr)*32 + lg*8]);
    #pragma unroll
    for (int mi = 0; mi < 4; mi++)
      #pragma unroll
      for (int ni = 0; ni < 4; ni++)
        acc[mi][ni] = MFMA16(a[mi], b[ni], acc[mi][ni]);
  }

  #pragma unroll
  for (int mi = 0; mi < 4; mi++){
    #pragma unroll
    for (int ni = 0; ni < 4; ni++){
      #pragma unroll
      for (int reg = 0; reg < 4; reg++){
        int m = m0 + wr*64 + mi*16 + lg*4 + reg;
        if (m >= MTOT) continue;
        int n = n0 + wc*64 + ni*16 + lr;
        float val = acc[mi][ni][reg] + bias[n];
        int b_ = m / NTOK, nidx = m % NTOK;
        int t = n >> 10, h = (n >> 6) & 15, d = n & 63;
        int bh = h * BATCH + b_;
        if (t == 0){
          qb[(size_t)(bh * NPAD + nidx) * 64 + d] = f2bf(val * SCALE_Q);
        } else if (t == 1){
          kb[(size_t)(bh * NPAD + nidx) * 64 + d] = f2bf(val);
        } else {
          vt[(size_t)(bh * 64 + d) * NPAD + nidx] = f2bf(val);
        }
      }
    }
  }
}

// ---------------- flash attention v5: swapped QK^T, P direct to PV (K=16 MFMA), no P-LDS ----------------
__global__ __launch_bounds__(256,3) void attn_kernel(
    const unsigned short* __restrict__ qb,
    const unsigned short* __restrict__ kb,
    const unsigned short* __restrict__ vt,
    const float* __restrict__ rph,   // [63][64]
    const float* __restrict__ rpw,   // [63][64]
    unsigned short* __restrict__ ao) // [MPAD][1024], rows b*NTOK+n
{
  __shared__ __align__(16) unsigned short Ks[2][64*64];   // 16 KB, XOR-swizzled chunks
  __shared__ __align__(16) unsigned short Vs[2][64*64];   // 16 KB
  __shared__ unsigned short RHt[32*128];                  // [kh][qrow] bf16 (x log2e)
  __shared__ unsigned short RWc[32*128];                  // [kw][qrow] bf16 (x log2e)

  int id = blockIdx.x;
  int work = (id & 7) * 144 + (id >> 3);
  int bh = work / 9;            // 0..127
  int qt = work % 9;            // 0..8 (128 q-rows each)
  int tid = threadIdx.x, w = tid >> 6, lane = tid & 63, lr = lane & 15, lg = lane >> 4;
  int h = bh >> 3, b_ = bh & 7;

  const unsigned short* qbase = qb + (size_t)bh * NPAD * 64;
  const unsigned short* kbase = kb + (size_t)bh * NPAD * 64;
  const unsigned short* vbase = vt + (size_t)bh * 64 * NPAD;

  // ---- stage kt=0 ----
  #pragma unroll
  for (int t = 0; t < 2; t++){
    int i = t*256 + tid;
    int row = i >> 3, cs = (i & 7) ^ (row & 7);
    gl_lds16(&kbase[(size_t)row*64 + cs*8],   &Ks[0][(t*256 + w*64)*8]);
    gl_lds16(&vbase[(size_t)row*NPAD + cs*8], &Vs[0][(t*256 + w*64)*8]);
  }

  // ---- Q fragments (B-operand of swapped QK^T): wave w owns q-rows [w*32, w*32+32) ----
  us8 aq[2][2];
  #pragma unroll
  for (int qf = 0; qf < 2; qf++){
    int qrow = qt*128 + w*32 + qf*16 + lr;
    aq[qf][0] = *reinterpret_cast<const us8*>(&qbase[(size_t)qrow*64 + lg*8]);
    aq[qf][1] = *reinterpret_cast<const us8*>(&qbase[(size_t)qrow*64 + 32 + lg*8]);
  }

  float rwreg[2][2][4] = {};   // [qf][kw>=16][reg], preloaded (kt-independent)

  // ---- rel-pos tables, transposed: RHt[kh][qrow], RWc[kw][qrow] ----
  if (qt < 8){
    int qh = qt*4 + w;     // wave-uniform
    // RH: t = nf2*16+lr rows of rph[qh-t+31]
    f32x4 accH[2][2] = {};
    #pragma unroll
    for (int ks = 0; ks < 2; ks++){
      #pragma unroll
      for (int nf2 = 0; nf2 < 2; nf2++){
        int t = nf2*16 + lr;
        const float* src = rph + (size_t)(qh - t + 31)*64 + ks*32 + lg*8;
        us8 ar;
        #pragma unroll
        for (int j = 0; j < 8; j++) ar[j] = f2bf(src[j]);
        #pragma unroll
        for (int qf = 0; qf < 2; qf++) accH[qf][nf2] = MFMA16(ar, aq[qf][ks], accH[qf][nf2]);
      }
    }
    #pragma unroll
    for (int qf = 0; qf < 2; qf++)
      #pragma unroll
      for (int nf2 = 0; nf2 < 2; nf2++)
        #pragma unroll
        for (int reg = 0; reg < 4; reg++){
          int t_out = nf2*16 + lg*4 + reg;        // kh 0..31
          RHt[t_out*128 + w*32 + qf*16 + lr] = f2bf(accH[qf][nf2][reg] * 8.0f);
        }
    // RW: t = nf*16+lr rows of rpw[t]; compact kw = qw - t + 31
    f32x4 accW[2][4] = {};
    #pragma unroll
    for (int ks = 0; ks < 2; ks++){
      #pragma unroll
      for (int nf = 0; nf < 4; nf++){
        int t = nf*16 + lr;
        us8 aw_ = {};
        if (t < 63){
          const float* src = rpw + (size_t)t*64 + ks*32 + lg*8;
          #pragma unroll
          for (int j = 0; j < 8; j++) aw_[j] = f2bf(src[j]);
        }
        #pragma unroll
        for (int qf = 0; qf < 2; qf++) accW[qf][nf] = MFMA16(aw_, aq[qf][ks], accW[qf][nf]);
      }
    }
    #pragma unroll
    for (int qf = 0; qf < 2; qf++)
      #pragma unroll
      for (int nf = 0; nf < 4; nf++)
        #pragma unroll
        for (int reg = 0; reg < 4; reg++){
          int t_out = nf*16 + lg*4 + reg;
          int qw = qf*16 + lr;                     // qrow & 31
          int kw = qw - t_out + 31;
          if (kw >= 0 && kw < 32)
            RWc[kw*128 + w*32 + qf*16 + lr] = f2bf(accW[qf][nf][reg] * 8.0f);
        }
    // preload RW into regs (own-wave LDS, in-wave ordering suffices)
    #pragma unroll
    for (int qf = 0; qf < 2; qf++)
      #pragma unroll
      for (int hf = 0; hf < 2; hf++)
        #pragma unroll
        for (int reg = 0; reg < 4; reg++)
          rwreg[qf][hf][reg] = bf2f(RWc[(hf*16 + lg*4 + reg)*128 + w*32 + qf*16 + lr]);
  }
  __syncthreads();   // drains stage-0

  f32x4 O[2][4] = {};
  f32x4 lac[2] = {};
  s4 ones4;
  ones4.x = (short)0x3F80; ones4.y = (short)0x3F80; ones4.z = (short)0x3F80; ones4.w = (short)0x3F80;

  for (int kt = 0; kt < 17; kt++){
    int cur = kt & 1;
    if (kt < 16){
      #pragma unroll
      for (int t = 0; t < 2; t++){
        int i = t*256 + tid;
        int row = i >> 3, cs = (i & 7) ^ (row & 7);
        gl_lds16(&kbase[(size_t)((kt+1)*64 + row)*64 + cs*8], &Ks[cur^1][(t*256 + w*64)*8]);
        gl_lds16(&vbase[(size_t)row*NPAD + (kt+1)*64 + cs*8], &Vs[cur^1][(t*256 + w*64)*8]);
      }
    }

    // ---- swapped QK^T: St[key][qrow] = K x Q^T ----
    f32x4 S[2][4] = {};
    __builtin_amdgcn_s_setprio(1);
    #pragma unroll
    for (int ks = 0; ks < 2; ks++)
      #pragma unroll
      for (int nf = 0; nf < 4; nf++){
        us8 bk = *reinterpret_cast<const us8*>(
            &Ks[cur][(nf*16 + lr)*64 + (((ks*4 + lg) ^ (lr & 7)) * 8)]);
        S[0][nf] = MFMA16(bk, aq[0][ks], S[0][nf]);
        S[1][nf] = MFMA16(bk, aq[1][ks], S[1][nf]);
      }
    __builtin_amdgcn_s_setprio(0);

    // ---- softmax (no-max): p = exp2(St + bias'), pack to bf16x4 A-frags in-register ----
    bool gk = (qt < 8) && (kt < 16);
    float rh2[2][2];
    #pragma unroll
    for (int qf = 0; qf < 2; qf++)
      #pragma unroll
      for (int hf = 0; hf < 2; hf++)
        rh2[qf][hf] = gk ? (bf2f(RHt[(kt*2 + hf)*128 + w*32 + qf*16 + lr]) - C2) : -C2;

    s4 pa[2][4];
    #pragma unroll
    for (int qf = 0; qf < 2; qf++){
      #pragma unroll
      for (int nf = 0; nf < 4; nf++){
        float pv[4];
        #pragma unroll
        for (int reg = 0; reg < 4; reg++){
          float logit = S[qf][nf][reg] + rh2[qf][nf>>1] + (gk ? rwreg[qf][nf&1][reg] : 0.f);
          float p = __builtin_amdgcn_exp2f(logit);
          int key = kt*64 + nf*16 + lg*4 + reg;
          pv[reg] = (key < NTOK) ? p : 0.f;
        }
        unsigned int u0 = __builtin_amdgcn_perm(
            __builtin_bit_cast(unsigned int, pv[1]), __builtin_bit_cast(unsigned int, pv[0]), 0x07060302u);
        unsigned int u1 = __builtin_amdgcn_perm(
            __builtin_bit_cast(unsigned int, pv[3]), __builtin_bit_cast(unsigned int, pv[2]), 0x07060302u);
        uint2 uu; uu.x = u0; uu.y = u1;
        pa[qf][nf] = __builtin_bit_cast(s4, uu);
      }
    }

    // ---- PV + l: K=16 MFMAs, P straight from registers ----
    __builtin_amdgcn_s_setprio(1);
    #pragma unroll
    for (int qf = 0; qf < 2; qf++)
      #pragma unroll
      for (int nf = 0; nf < 4; nf++)
        lac[qf] = MFMAH(pa[qf][nf], ones4, lac[qf]);
    #pragma unroll
    for (int nf = 0; nf < 4; nf++){
      #pragma unroll
      for (int nfd = 0; nfd < 4; nfd++){
        us4 bv = *reinterpret_cast<const us4*>(
            &Vs[cur][(nfd*16 + lr)*64 + (((nf*2 + (lg>>1)) ^ (lr & 7))*8) + (lg&1)*4]);
        O[0][nfd] = MFMAH(pa[0][nf], bv, O[0][nfd]);
        O[1][nfd] = MFMAH(pa[1][nf], bv, O[1][nfd]);
      }
    }
    __builtin_amdgcn_s_setprio(0);
    __syncthreads();   // drains next-tile stage; protects dbuf reuse
  }

  // ---- epilogue: O rows = qrow (lg*4+reg), cols = d (lr). lac aligned with O rows. ----
  #pragma unroll
  for (int qf = 0; qf < 2; qf++)
    #pragma unroll
    for (int reg = 0; reg < 4; reg++){
      int qg = qt*128 + w*32 + qf*16 + lg*4 + reg;
      if (qg < NTOK){
        float inv = 1.0f / lac[qf][reg];
        #pragma unroll
        for (int nfd = 0; nfd < 4; nfd++)
          ao[(size_t)(b_ * NTOK + qg) * 1024 + h*64 + nfd*16 + lr] = f2bf(O[qf][nfd][reg] * inv);
      }
    }
}

// ---------------- proj GEMM (m97 structure + XCD swizzle): out[MTOT][1024] = A * W^T + b ----------------
__global__ __launch_bounds__(256,2) void proj_gemm(
    const unsigned short* __restrict__ A,   // [MPAD][1024]
    const unsigned short* __restrict__ Bw,  // [1024][1024]
    const float* __restrict__ bias,
    float* __restrict__ out)
{
  const int K = 1024;
  __shared__ __align__(16) unsigned short As[128*32];
  __shared__ __align__(16) unsigned short Bs[128*32];
  int tid = threadIdx.x;
  int id = blockIdx.x;
  int work = (id & 7) * 65 + (id >> 3);
  int m0 = (work / 8) * 128, n0 = (work % 8) * 128;
  int w = tid >> 6, lane = tid & 63, lr = lane & 15, lg = lane >> 4;
  int wr = w >> 1, wc = w & 1;
  int srow = lane >> 2, scol = (lane & 3) * 8;
  f32x4 acc[4][4] = {};

  for (int k0 = 0; k0 < K; k0 += 32){
    __syncthreads();
    #pragma unroll
    for (int i = 0; i < 2; i++){
      int q = w * 2 + i;
      gl_lds16(&A [(size_t)(m0 + q*16 + srow) * K + k0 + scol], &As[q*512]);
      gl_lds16(&Bw[(size_t)(n0 + q*16 + srow) * K + k0 + scol], &Bs[q*512]);
    }
    __syncthreads();
    us8 a[4], b[4];
    #pragma unroll
    for (int mi = 0; mi < 4; mi++) a[mi] = *reinterpret_cast<const us8*>(&As[(wr*64 + mi*16 + lr)*32 + lg*8]);
    #pragma unroll
    for (int ni = 0; ni < 4; ni++) b[ni] = *reinterpret_cast<const us8*>(&Bs[(wc*64 + ni*16 + lr)*32 + lg*8]);
    #pragma unroll
    for (int mi = 0; mi < 4; mi++)
      #pragma unroll
      for (int ni = 0; ni < 4; ni++)
        acc[mi][ni] = MFMA16(a[mi], b[ni], acc[mi][ni]);
  }

  #pragma unroll
  for (int mi = 0; mi < 4; mi++){
    #pragma unroll
    for (int ni = 0; ni < 4; ni++){
      #pragma unroll
      for (int reg = 0; reg < 4; reg++){
        int m = m0 + wr*64 + mi*16 + lg*4 + reg;
        if (m >= MTOT) continue;
        int n = n0 + wc*64 + ni*16 + lr;
        out[(size_t)m * 1024 + n] = acc[mi][ni][reg] + bias[n];
      }
    }
  }
}

extern "C" void kernel_launch(void* const* d_in, const int* in_sizes, int n_in,
                              void* d_out, int out_size, void* d_ws, size_t ws_size,
                              hipStream_t stream)
{
  const float* x      = (const float*)d_in[0];
  const float* qkv_w  = (const float*)d_in[1];
  const float* qkv_b  = (const float*)d_in[2];
  const float* proj_w = (const float*)d_in[3];
  const float* proj_b = (const float*)d_in[4];
  const float* rph    = (const float*)d_in[5];
  const float* rpw    = (const float*)d_in[6];
  float* out = (float*)d_out;

  char* ws = (char*)d_ws;
  size_t off = 0;
  auto alloc = [&](size_t bytes){ char* p = ws + off; off += (bytes + 255) & ~(size_t)255; return p; };
  unsigned short* x_bf  = (unsigned short*)alloc((size_t)MPAD * 1024 * 2);
  unsigned short* qw_bf = (unsigned short*)alloc((size_t)3072 * 1024 * 2);
  unsigned short* pw_bf = (unsigned short*)alloc((size_t)1024 * 1024 * 2);
  unsigned short* qbuf  = (unsigned short*)alloc((size_t)128 * NPAD * 64 * 2);
  unsigned short* kbuf  = (unsigned short*)alloc((size_t)128 * NPAD * 64 * 2);
  unsigned short* vtbuf = (unsigned short*)alloc((size_t)128 * 64 * NPAD * 2);
  unsigned short* aout  = (unsigned short*)alloc((size_t)MPAD * 1024 * 2);
  if (off > ws_size) return;   // workspace too small: fail visibly

  int n4x = MTOT * 1024 / 4;
  cvt_f32_bf16<<<dim3((n4x + 255) / 256), 256, 0, stream>>>(x, x_bf, n4x);
  int n4q = 3072 * 1024 / 4;
  cvt_f32_bf16<<<dim3((n4q + 255) / 256), 256, 0, stream>>>(qkv_w, qw_bf, n4q);
  int n4p = 1024 * 1024 / 4;
  cvt_f32_bf16<<<dim3((n4p + 255) / 256), 256, 0, stream>>>(proj_w, pw_bf, n4p);

  int npad = 128 * (NPAD - NTOK) * 64 + 2 * (MPAD - MTOT) * 1024;
  pad_zero<<<dim3((npad + 255) / 256), 256, 0, stream>>>(qbuf, kbuf, vtbuf, x_bf, aout);

  qkv_gemm<<<dim3(1560), 256, 0, stream>>>(x_bf, qw_bf, qkv_b, qbuf, kbuf, vtbuf);
  attn_kernel<<<dim3(1152), 256, 0, stream>>>(qbuf, kbuf, vtbuf, rph, rpw, aout);
  proj_gemm<<<dim3(520), 256, 0, stream>>>(aout, pw_bf, proj_b, out);
}

// Round 6
// 230.877 us; speedup vs baseline: 2.2703x; 1.0441x over previous
//
#include <hip/hip_runtime.h>

#define BATCH 8
#define NTOK 1032
#define NPAD 1152
#define MTOT (BATCH*NTOK)   // 8256
#define MPAD 8320           // 65 * 128

#define SCALE_Q 0.18033688011112042f   // 0.125 * log2(e)
#define C2      5.770780163555854f     // 4 * log2(e)

typedef __bf16 bf16x8 __attribute__((ext_vector_type(8)));
typedef float f32x4 __attribute__((ext_vector_type(4)));
typedef unsigned short us8 __attribute__((ext_vector_type(8)));
typedef unsigned short us4 __attribute__((ext_vector_type(4)));
typedef short s4 __attribute__((ext_vector_type(4)));

__device__ __forceinline__ unsigned short f2bf(float f){
  unsigned int u = __builtin_bit_cast(unsigned int, f);
  u += 0x7fffu + ((u >> 16) & 1u);          // RNE
  return (unsigned short)(u >> 16);
}
__device__ __forceinline__ float bf2f(unsigned short u){
  return __builtin_bit_cast(float, (unsigned int)u << 16);
}

#define MFMA16(a,b,c) __builtin_amdgcn_mfma_f32_16x16x32_bf16( \
    __builtin_bit_cast(bf16x8,(a)), __builtin_bit_cast(bf16x8,(b)), (c), 0, 0, 0)
// K=16 variant: A/B are 4 bf16 (2 VGPR)
#define MFMAH(a,b,c) __builtin_amdgcn_mfma_f32_16x16x16bf16_1k( \
    __builtin_bit_cast(s4,(a)), __builtin_bit_cast(s4,(b)), (c), 0, 0, 0)

// async global->LDS, 16B per lane, dest = wave-uniform base + lane*16
__device__ __forceinline__ void gl_lds16(const unsigned short* g, unsigned short* l){
  __builtin_amdgcn_global_load_lds(
      (const __attribute__((address_space(1))) unsigned int*)g,
      (__attribute__((address_space(3))) unsigned int*)l, 16, 0, 0);
}

// ---------------- fp32 -> bf16 conversion ----------------
__global__ __launch_bounds__(256) void cvt_f32_bf16(const float* __restrict__ in,
                                                    unsigned short* __restrict__ out, int n4){
  int i = blockIdx.x * 256 + threadIdx.x;
  if (i < n4){
    float4 v = reinterpret_cast<const float4*>(in)[i];
    us4 o; o.x = f2bf(v.x); o.y = f2bf(v.y); o.z = f2bf(v.z); o.w = f2bf(v.w);
    reinterpret_cast<us4*>(out)[i] = o;
  }
}

// ---------------- zero all padded regions ----------------
__global__ __launch_bounds__(256) void pad_zero(unsigned short* __restrict__ qb,
                                                unsigned short* __restrict__ kb,
                                                unsigned short* __restrict__ xb,
                                                unsigned short* __restrict__ ao){
  int i = blockIdx.x * 256 + threadIdx.x;
  const int t1 = 128 * (NPAD - NTOK) * 64;          // q/k pad rows
  const int t2 = t1 + (MPAD - MTOT) * 1024;         // x_bf pad rows
  const int t3 = t2 + (MPAD - MTOT) * 1024;         // aout pad rows
  if (i < t1){
    int bh = i / ((NPAD - NTOK) * 64);
    int r  = (i / 64) % (NPAD - NTOK);
    int d  = i % 64;
    int idx = (bh * NPAD + NTOK + r) * 64 + d;
    qb[idx] = 0;
    kb[idx] = 0;
  } else if (i < t2){
    xb[(size_t)MTOT * 1024 + (i - t1)] = 0;
  } else if (i < t3){
    ao[(size_t)MTOT * 1024 + (i - t2)] = 0;
  }
}

// ---------------- QKV GEMM (2-phase dbuf + XCD swizzle): C[MPAD][3072] = A * W^T ----------------
__global__ __launch_bounds__(256,3) void qkv_gemm(
    const unsigned short* __restrict__ A,   // [MPAD][1024] bf16
    const unsigned short* __restrict__ Bw,  // [3072][1024] bf16
    const float* __restrict__ bias,         // [3072]
    unsigned short* __restrict__ qb,        // [128][NPAD][64]  (q pre-scaled by SCALE_Q)
    unsigned short* __restrict__ kb,        // [128][NPAD][64]
    unsigned short* __restrict__ vb)        // [128][NTOK][64]  (normal layout; transposed later)
{
  const int K = 1024;
  __shared__ __align__(16) unsigned short As[2][128*32];
  __shared__ __align__(16) unsigned short Bs[2][128*32];
  int tid = threadIdx.x;
  int id = blockIdx.x;
  int work = (id & 7) * 195 + (id >> 3);
  int m0 = (work / 24) * 128, n0 = (work % 24) * 128;
  int w = tid >> 6, lane = tid & 63, lr = lane & 15, lg = lane >> 4;
  int wr = w >> 1, wc = w & 1;
  int srow = lane >> 2, scol = (lane & 3) * 8;
  f32x4 acc[4][4] = {};

  // prologue: stage k-tile 0 into buf 0
  #pragma unroll
  for (int i = 0; i < 2; i++){
    int q = w * 2 + i;
    gl_lds16(&A [(size_t)(m0 + q*16 + srow) * K + scol], &As[0][q*512]);
    gl_lds16(&Bw[(size_t)(n0 + q*16 + srow) * K + scol], &Bs[0][q*512]);
  }
  __syncthreads();

  for (int kt = 0; kt < 32; kt++){
    int cur = kt & 1;
    if (kt < 31){
      int k0 = (kt + 1) * 32;
      #pragma unroll
      for (int i = 0; i < 2; i++){
        int q = w * 2 + i;
        gl_lds16(&A [(size_t)(m0 + q*16 + srow) * K + k0 + scol], &As[cur^1][q*512]);
        gl_lds16(&Bw[(size_t)(n0 + q*16 + srow) * K + k0 + scol], &Bs[cur^1][q*512]);
      }
    }
    us8 a[4], b[4];
    #pragma unroll
    for (int mi = 0; mi < 4; mi++) a[mi] = *reinterpret_cast<const us8*>(&As[cur][(wr*64 + mi*16 + lr)*32 + lg*8]);
    #pragma unroll
    for (int ni = 0; ni < 4; ni++) b[ni] = *reinterpret_cast<const us8*>(&Bs[cur][(wc*64 + ni*16 + lr)*32 + lg*8]);
    #pragma unroll
    for (int mi = 0; mi < 4; mi++)
      #pragma unroll
      for (int ni = 0; ni < 4; ni++)
        acc[mi][ni] = MFMA16(a[mi], b[ni], acc[mi][ni]);
    __syncthreads();   // drains next-tile loads (they had the whole compute to land)
  }

  // epilogue: q/k into padded [bh][n][64]; v into normal [bh][n][64]
  #pragma unroll
  for (int mi = 0; mi < 4; mi++){
    #pragma unroll
    for (int ni = 0; ni < 4; ni++){
      #pragma unroll
      for (int reg = 0; reg < 4; reg++){
        int m = m0 + wr*64 + mi*16 + lg*4 + reg;
        if (m >= MTOT) continue;
        int n = n0 + wc*64 + ni*16 + lr;
        float val = acc[mi][ni][reg] + bias[n];
        int b_ = m / NTOK, nidx = m % NTOK;
        int t = n >> 10, h = (n >> 6) & 15, d = n & 63;
        int bh = h * BATCH + b_;
        if (t == 0){
          qb[(size_t)(bh * NPAD + nidx) * 64 + d] = f2bf(val * SCALE_Q);
        } else if (t == 1){
          kb[(size_t)(bh * NPAD + nidx) * 64 + d] = f2bf(val);
        } else {
          vb[(size_t)(bh * NTOK + nidx) * 64 + d] = f2bf(val);
        }
      }
    }
  }
}

// ---------------- V transpose: vb [bh][n][64] -> vt [bh][64][NPAD] ----------------
__global__ __launch_bounds__(256) void transpose_v(const unsigned short* __restrict__ vb,
                                                   unsigned short* __restrict__ vt){
  __shared__ unsigned short Ls[64][72];
  int blk = blockIdx.x;
  int bh = blk / 17, tl = blk % 17;       // 17 tiles cover keys 0..1088
  int n0 = tl * 64;
  int t = threadIdx.x;

  #pragma unroll
  for (int p = 0; p < 2; p++){
    int idx = p * 256 + t;                // 512 chunks: r = idx>>3, c = idx&7
    int r = idx >> 3, c = idx & 7;
    us8 v = {};
    if (n0 + r < NTOK)
      v = *reinterpret_cast<const us8*>(&vb[((size_t)bh * NTOK + n0 + r) * 64 + c * 8]);
    *reinterpret_cast<us8*>(&Ls[r][c * 8]) = v;
  }
  __syncthreads();

  int d = t & 63, ng = t >> 6;            // each thread: row d, 16 n-values
  us8 o[2];
  #pragma unroll
  for (int hf = 0; hf < 2; hf++){
    #pragma unroll
    for (int j = 0; j < 8; j++) o[hf][j] = Ls[ng*16 + hf*8 + j][d];
    *reinterpret_cast<us8*>(&vt[((size_t)bh * 64 + d) * NPAD + n0 + ng*16 + hf*8]) = o[hf];
  }
}

// ---------------- flash attention v5: swapped QK^T, P direct to PV (K=16 MFMA), no P-LDS ----------------
__global__ __launch_bounds__(256,3) void attn_kernel(
    const unsigned short* __restrict__ qb,
    const unsigned short* __restrict__ kb,
    const unsigned short* __restrict__ vt,
    const float* __restrict__ rph,   // [63][64]
    const float* __restrict__ rpw,   // [63][64]
    unsigned short* __restrict__ ao) // [MPAD][1024], rows b*NTOK+n
{
  __shared__ __align__(16) unsigned short Ks[2][64*64];   // 16 KB, XOR-swizzled chunks
  __shared__ __align__(16) unsigned short Vs[2][64*64];   // 16 KB
  __shared__ unsigned short RHt[32*128];                  // [kh][qrow] bf16 (x log2e)
  __shared__ unsigned short RWc[32*128];                  // [kw][qrow] bf16 (x log2e)

  int id = blockIdx.x;
  int work = (id & 7) * 144 + (id >> 3);
  int bh = work / 9;            // 0..127
  int qt = work % 9;            // 0..8 (128 q-rows each)
  int tid = threadIdx.x, w = tid >> 6, lane = tid & 63, lr = lane & 15, lg = lane >> 4;
  int h = bh >> 3, b_ = bh & 7;

  const unsigned short* qbase = qb + (size_t)bh * NPAD * 64;
  const unsigned short* kbase = kb + (size_t)bh * NPAD * 64;
  const unsigned short* vbase = vt + (size_t)bh * 64 * NPAD;

  // ---- stage kt=0 ----
  #pragma unroll
  for (int t = 0; t < 2; t++){
    int i = t*256 + tid;
    int row = i >> 3, cs = (i & 7) ^ (row & 7);
    gl_lds16(&kbase[(size_t)row*64 + cs*8],   &Ks[0][(t*256 + w*64)*8]);
    gl_lds16(&vbase[(size_t)row*NPAD + cs*8], &Vs[0][(t*256 + w*64)*8]);
  }

  // ---- Q fragments (B-operand of swapped QK^T): wave w owns q-rows [w*32, w*32+32) ----
  us8 aq[2][2];
  #pragma unroll
  for (int qf = 0; qf < 2; qf++){
    int qrow = qt*128 + w*32 + qf*16 + lr;
    aq[qf][0] = *reinterpret_cast<const us8*>(&qbase[(size_t)qrow*64 + lg*8]);
    aq[qf][1] = *reinterpret_cast<const us8*>(&qbase[(size_t)qrow*64 + 32 + lg*8]);
  }

  float rwreg[2][2][4] = {};   // [qf][kw>=16][reg], preloaded (kt-independent)

  // ---- rel-pos tables, transposed: RHt[kh][qrow], RWc[kw][qrow] ----
  if (qt < 8){
    int qh = qt*4 + w;     // wave-uniform
    f32x4 accH[2][2] = {};
    #pragma unroll
    for (int ks = 0; ks < 2; ks++){
      #pragma unroll
      for (int nf2 = 0; nf2 < 2; nf2++){
        int t = nf2*16 + lr;
        const float* src = rph + (size_t)(qh - t + 31)*64 + ks*32 + lg*8;
        us8 ar;
        #pragma unroll
        for (int j = 0; j < 8; j++) ar[j] = f2bf(src[j]);
        #pragma unroll
        for (int qf = 0; qf < 2; qf++) accH[qf][nf2] = MFMA16(ar, aq[qf][ks], accH[qf][nf2]);
      }
    }
    #pragma unroll
    for (int qf = 0; qf < 2; qf++)
      #pragma unroll
      for (int nf2 = 0; nf2 < 2; nf2++)
        #pragma unroll
        for (int reg = 0; reg < 4; reg++){
          int t_out = nf2*16 + lg*4 + reg;        // kh 0..31
          RHt[t_out*128 + w*32 + qf*16 + lr] = f2bf(accH[qf][nf2][reg] * 8.0f);
        }
    f32x4 accW[2][4] = {};
    #pragma unroll
    for (int ks = 0; ks < 2; ks++){
      #pragma unroll
      for (int nf = 0; nf < 4; nf++){
        int t = nf*16 + lr;
        us8 aw_ = {};
        if (t < 63){
          const float* src = rpw + (size_t)t*64 + ks*32 + lg*8;
          #pragma unroll
          for (int j = 0; j < 8; j++) aw_[j] = f2bf(src[j]);
        }
        #pragma unroll
        for (int qf = 0; qf < 2; qf++) accW[qf][nf] = MFMA16(aw_, aq[qf][ks], accW[qf][nf]);
      }
    }
    #pragma unroll
    for (int qf = 0; qf < 2; qf++)
      #pragma unroll
      for (int nf = 0; nf < 4; nf++)
        #pragma unroll
        for (int reg = 0; reg < 4; reg++){
          int t_out = nf*16 + lg*4 + reg;
          int qw = qf*16 + lr;                     // qrow & 31
          int kw = qw - t_out + 31;
          if (kw >= 0 && kw < 32)
            RWc[kw*128 + w*32 + qf*16 + lr] = f2bf(accW[qf][nf][reg] * 8.0f);
        }
    // preload RW into regs (own-wave LDS, in-wave ordering suffices)
    #pragma unroll
    for (int qf = 0; qf < 2; qf++)
      #pragma unroll
      for (int hf = 0; hf < 2; hf++)
        #pragma unroll
        for (int reg = 0; reg < 4; reg++)
          rwreg[qf][hf][reg] = bf2f(RWc[(hf*16 + lg*4 + reg)*128 + w*32 + qf*16 + lr]);
  }
  __syncthreads();   // drains stage-0

  f32x4 O[2][4] = {};
  f32x4 lac[2] = {};
  s4 ones4;
  ones4.x = (short)0x3F80; ones4.y = (short)0x3F80; ones4.z = (short)0x3F80; ones4.w = (short)0x3F80;

  for (int kt = 0; kt < 17; kt++){
    int cur = kt & 1;
    if (kt < 16){
      #pragma unroll
      for (int t = 0; t < 2; t++){
        int i = t*256 + tid;
        int row = i >> 3, cs = (i & 7) ^ (row & 7);
        gl_lds16(&kbase[(size_t)((kt+1)*64 + row)*64 + cs*8], &Ks[cur^1][(t*256 + w*64)*8]);
        gl_lds16(&vbase[(size_t)row*NPAD + (kt+1)*64 + cs*8], &Vs[cur^1][(t*256 + w*64)*8]);
      }
    }

    // ---- swapped QK^T: St[key][qrow] = K x Q^T ----
    f32x4 S[2][4] = {};
    __builtin_amdgcn_s_setprio(1);
    #pragma unroll
    for (int ks = 0; ks < 2; ks++)
      #pragma unroll
      for (int nf = 0; nf < 4; nf++){
        us8 bk = *reinterpret_cast<const us8*>(
            &Ks[cur][(nf*16 + lr)*64 + (((ks*4 + lg) ^ (lr & 7)) * 8)]);
        S[0][nf] = MFMA16(bk, aq[0][ks], S[0][nf]);
        S[1][nf] = MFMA16(bk, aq[1][ks], S[1][nf]);
      }
    __builtin_amdgcn_s_setprio(0);

    // ---- softmax (no-max): p = exp2(St + bias'), pack to bf16x4 A-frags in-register ----
    bool gk = (qt < 8) && (kt < 16);
    float rh2[2][2];
    #pragma unroll
    for (int qf = 0; qf < 2; qf++)
      #pragma unroll
      for (int hf = 0; hf < 2; hf++)
        rh2[qf][hf] = gk ? (bf2f(RHt[(kt*2 + hf)*128 + w*32 + qf*16 + lr]) - C2) : -C2;

    s4 pa[2][4];
    #pragma unroll
    for (int qf = 0; qf < 2; qf++){
      #pragma unroll
      for (int nf = 0; nf < 4; nf++){
        float pv[4];
        #pragma unroll
        for (int reg = 0; reg < 4; reg++){
          float logit = S[qf][nf][reg] + rh2[qf][nf>>1] + (gk ? rwreg[qf][nf&1][reg] : 0.f);
          float p = __builtin_amdgcn_exp2f(logit);
          int key = kt*64 + nf*16 + lg*4 + reg;
          pv[reg] = (key < NTOK) ? p : 0.f;
        }
        unsigned int u0 = __builtin_amdgcn_perm(
            __builtin_bit_cast(unsigned int, pv[1]), __builtin_bit_cast(unsigned int, pv[0]), 0x07060302u);
        unsigned int u1 = __builtin_amdgcn_perm(
            __builtin_bit_cast(unsigned int, pv[3]), __builtin_bit_cast(unsigned int, pv[2]), 0x07060302u);
        uint2 uu; uu.x = u0; uu.y = u1;
        pa[qf][nf] = __builtin_bit_cast(s4, uu);
      }
    }

    // ---- PV + l: K=16 MFMAs, P straight from registers ----
    __builtin_amdgcn_s_setprio(1);
    #pragma unroll
    for (int qf = 0; qf < 2; qf++)
      #pragma unroll
      for (int nf = 0; nf < 4; nf++)
        lac[qf] = MFMAH(pa[qf][nf], ones4, lac[qf]);
    #pragma unroll
    for (int nf = 0; nf < 4; nf++){
      #pragma unroll
      for (int nfd = 0; nfd < 4; nfd++){
        us4 bv = *reinterpret_cast<const us4*>(
            &Vs[cur][(nfd*16 + lr)*64 + (((nf*2 + (lg>>1)) ^ (lr & 7))*8) + (lg&1)*4]);
        O[0][nfd] = MFMAH(pa[0][nf], bv, O[0][nfd]);
        O[1][nfd] = MFMAH(pa[1][nf], bv, O[1][nfd]);
      }
    }
    __builtin_amdgcn_s_setprio(0);
    __syncthreads();   // drains next-tile stage; protects dbuf reuse
  }

  // ---- epilogue: O rows = qrow (lg*4+reg), cols = d (lr). lac aligned with O rows. ----
  #pragma unroll
  for (int qf = 0; qf < 2; qf++)
    #pragma unroll
    for (int reg = 0; reg < 4; reg++){
      int qg = qt*128 + w*32 + qf*16 + lg*4 + reg;
      if (qg < NTOK){
        float inv = 1.0f / lac[qf][reg];
        #pragma unroll
        for (int nfd = 0; nfd < 4; nfd++)
          ao[(size_t)(b_ * NTOK + qg) * 1024 + h*64 + nfd*16 + lr] = f2bf(O[qf][nfd][reg] * inv);
      }
    }
}

// ---------------- proj GEMM (2-phase dbuf + XCD swizzle): out[MTOT][1024] = A * W^T + b ----------------
__global__ __launch_bounds__(256,3) void proj_gemm(
    const unsigned short* __restrict__ A,   // [MPAD][1024]
    const unsigned short* __restrict__ Bw,  // [1024][1024]
    const float* __restrict__ bias,
    float* __restrict__ out)
{
  const int K = 1024;
  __shared__ __align__(16) unsigned short As[2][128*32];
  __shared__ __align__(16) unsigned short Bs[2][128*32];
  int tid = threadIdx.x;
  int id = blockIdx.x;
  int work = (id & 7) * 65 + (id >> 3);
  int m0 = (work / 8) * 128, n0 = (work % 8) * 128;
  int w = tid >> 6, lane = tid & 63, lr = lane & 15, lg = lane >> 4;
  int wr = w >> 1, wc = w & 1;
  int srow = lane >> 2, scol = (lane & 3) * 8;
  f32x4 acc[4][4] = {};

  #pragma unroll
  for (int i = 0; i < 2; i++){
    int q = w * 2 + i;
    gl_lds16(&A [(size_t)(m0 + q*16 + srow) * K + scol], &As[0][q*512]);
    gl_lds16(&Bw[(size_t)(n0 + q*16 + srow) * K + scol], &Bs[0][q*512]);
  }
  __syncthreads();

  for (int kt = 0; kt < 32; kt++){
    int cur = kt & 1;
    if (kt < 31){
      int k0 = (kt + 1) * 32;
      #pragma unroll
      for (int i = 0; i < 2; i++){
        int q = w * 2 + i;
        gl_lds16(&A [(size_t)(m0 + q*16 + srow) * K + k0 + scol], &As[cur^1][q*512]);
        gl_lds16(&Bw[(size_t)(n0 + q*16 + srow) * K + k0 + scol], &Bs[cur^1][q*512]);
      }
    }
    us8 a[4], b[4];
    #pragma unroll
    for (int mi = 0; mi < 4; mi++) a[mi] = *reinterpret_cast<const us8*>(&As[cur][(wr*64 + mi*16 + lr)*32 + lg*8]);
    #pragma unroll
    for (int ni = 0; ni < 4; ni++) b[ni] = *reinterpret_cast<const us8*>(&Bs[cur][(wc*64 + ni*16 + lr)*32 + lg*8]);
    #pragma unroll
    for (int mi = 0; mi < 4; mi++)
      #pragma unroll
      for (int ni = 0; ni < 4; ni++)
        acc[mi][ni] = MFMA16(a[mi], b[ni], acc[mi][ni]);
    __syncthreads();
  }

  #pragma unroll
  for (int mi = 0; mi < 4; mi++){
    #pragma unroll
    for (int ni = 0; ni < 4; ni++){
      #pragma unroll
      for (int reg = 0; reg < 4; reg++){
        int m = m0 + wr*64 + mi*16 + lg*4 + reg;
        if (m >= MTOT) continue;
        int n = n0 + wc*64 + ni*16 + lr;
        out[(size_t)m * 1024 + n] = acc[mi][ni][reg] + bias[n];
      }
    }
  }
}

extern "C" void kernel_launch(void* const* d_in, const int* in_sizes, int n_in,
                              void* d_out, int out_size, void* d_ws, size_t ws_size,
                              hipStream_t stream)
{
  const float* x      = (const float*)d_in[0];
  const float* qkv_w  = (const float*)d_in[1];
  const float* qkv_b  = (const float*)d_in[2];
  const float* proj_w = (const float*)d_in[3];
  const float* proj_b = (const float*)d_in[4];
  const float* rph    = (const float*)d_in[5];
  const float* rpw    = (const float*)d_in[6];
  float* out = (float*)d_out;

  char* ws = (char*)d_ws;
  size_t off = 0;
  auto alloc = [&](size_t bytes){ char* p = ws + off; off += (bytes + 255) & ~(size_t)255; return p; };
  unsigned short* x_bf  = (unsigned short*)alloc((size_t)MPAD * 1024 * 2);
  unsigned short* qw_bf = (unsigned short*)alloc((size_t)3072 * 1024 * 2);
  unsigned short* pw_bf = (unsigned short*)alloc((size_t)1024 * 1024 * 2);
  unsigned short* qbuf  = (unsigned short*)alloc((size_t)128 * NPAD * 64 * 2);
  unsigned short* kbuf  = (unsigned short*)alloc((size_t)128 * NPAD * 64 * 2);
  unsigned short* vtbuf = (unsigned short*)alloc((size_t)128 * 64 * NPAD * 2);
  unsigned short* aout  = (unsigned short*)alloc((size_t)MPAD * 1024 * 2);
  if (off > ws_size) return;   // workspace too small: fail visibly

  // vb (normal-layout V, 128*NTOK*64 bf16 = 16.9 MB) aliases the head of aout:
  // written by qkv_gemm, consumed by transpose_v BEFORE attn writes aout.
  // aout's pad region (rows >= MTOT) starts exactly at byte 128*NTOK*64*2 — no overlap.
  unsigned short* vbuf = aout;

  int n4x = MTOT * 1024 / 4;
  cvt_f32_bf16<<<dim3((n4x + 255) / 256), 256, 0, stream>>>(x, x_bf, n4x);
  int n4q = 3072 * 1024 / 4;
  cvt_f32_bf16<<<dim3((n4q + 255) / 256), 256, 0, stream>>>(qkv_w, qw_bf, n4q);
  int n4p = 1024 * 1024 / 4;
  cvt_f32_bf16<<<dim3((n4p + 255) / 256), 256, 0, stream>>>(proj_w, pw_bf, n4p);

  int npad = 128 * (NPAD - NTOK) * 64 + 2 * (MPAD - MTOT) * 1024;
  pad_zero<<<dim3((npad + 255) / 256), 256, 0, stream>>>(qbuf, kbuf, x_bf, aout);

  qkv_gemm<<<dim3(1560), 256, 0, stream>>>(x_bf, qw_bf, qkv_b, qbuf, kbuf, vbuf);
  transpose_v<<<dim3(128 * 17), 256, 0, stream>>>(vbuf, vtbuf);
  attn_kernel<<<dim3(1152), 256, 0, stream>>>(qbuf, kbuf, vtbuf, rph, rpw, aout);
  proj_gemm<<<dim3(520), 256, 0, stream>>>(aout, pw_bf, proj_b, out);
}

// Round 7
// 225.975 us; speedup vs baseline: 2.3195x; 1.0217x over previous
//
#include <hip/hip_runtime.h>

#define BATCH 8
#define NTOK 1032
#define NPAD 1152
#define MTOT (BATCH*NTOK)   // 8256
#define MPAD 8320           // 65 * 128

#define SCALE_Q 0.18033688011112042f   // 0.125 * log2(e)
#define C2      5.770780163555854f     // 4 * log2(e)

typedef __bf16 bf16x8 __attribute__((ext_vector_type(8)));
typedef float f32x4 __attribute__((ext_vector_type(4)));
typedef unsigned short us8 __attribute__((ext_vector_type(8)));
typedef unsigned short us4 __attribute__((ext_vector_type(4)));
typedef short s4 __attribute__((ext_vector_type(4)));

__device__ __forceinline__ unsigned short f2bf(float f){
  unsigned int u = __builtin_bit_cast(unsigned int, f);
  u += 0x7fffu + ((u >> 16) & 1u);          // RNE
  return (unsigned short)(u >> 16);
}
__device__ __forceinline__ float bf2f(unsigned short u){
  return __builtin_bit_cast(float, (unsigned int)u << 16);
}

#define MFMA16(a,b,c) __builtin_amdgcn_mfma_f32_16x16x32_bf16( \
    __builtin_bit_cast(bf16x8,(a)), __builtin_bit_cast(bf16x8,(b)), (c), 0, 0, 0)
// K=16 variant: A/B are 4 bf16 (2 VGPR)
#define MFMAH(a,b,c) __builtin_amdgcn_mfma_f32_16x16x16bf16_1k( \
    __builtin_bit_cast(s4,(a)), __builtin_bit_cast(s4,(b)), (c), 0, 0, 0)

// async global->LDS, 16B per lane, dest = wave-uniform base + lane*16
__device__ __forceinline__ void gl_lds16(const unsigned short* g, unsigned short* l){
  __builtin_amdgcn_global_load_lds(
      (const __attribute__((address_space(1))) unsigned int*)g,
      (__attribute__((address_space(3))) unsigned int*)l, 16, 0, 0);
}

// ---------------- fp32 -> bf16 conversion ----------------
__global__ __launch_bounds__(256) void cvt_f32_bf16(const float* __restrict__ in,
                                                    unsigned short* __restrict__ out, int n4){
  int i = blockIdx.x * 256 + threadIdx.x;
  if (i < n4){
    float4 v = reinterpret_cast<const float4*>(in)[i];
    us4 o; o.x = f2bf(v.x); o.y = f2bf(v.y); o.z = f2bf(v.z); o.w = f2bf(v.w);
    reinterpret_cast<us4*>(out)[i] = o;
  }
}

// ---------------- zero all padded regions ----------------
__global__ __launch_bounds__(256) void pad_zero(unsigned short* __restrict__ qb,
                                                unsigned short* __restrict__ kb,
                                                unsigned short* __restrict__ xb,
                                                unsigned short* __restrict__ ao){
  int i = blockIdx.x * 256 + threadIdx.x;
  const int t1 = 128 * (NPAD - NTOK) * 64;          // q/k pad rows
  const int t2 = t1 + (MPAD - MTOT) * 1024;         // x_bf pad rows
  const int t3 = t2 + (MPAD - MTOT) * 1024;         // aout pad rows
  if (i < t1){
    int bh = i / ((NPAD - NTOK) * 64);
    int r  = (i / 64) % (NPAD - NTOK);
    int d  = i % 64;
    int idx = (bh * NPAD + NTOK + r) * 64 + d;
    qb[idx] = 0;
    kb[idx] = 0;
  } else if (i < t2){
    xb[(size_t)MTOT * 1024 + (i - t1)] = 0;
  } else if (i < t3){
    ao[(size_t)MTOT * 1024 + (i - t2)] = 0;
  }
}

// ---------------- QKV GEMM (counted-vmcnt 2-phase + swizzled LDS + XCD swizzle) ----------------
__global__ __launch_bounds__(256,4) void qkv_gemm(
    const unsigned short* __restrict__ A,   // [MPAD][1024] bf16
    const unsigned short* __restrict__ Bw,  // [3072][1024] bf16
    const float* __restrict__ bias,         // [3072]
    unsigned short* __restrict__ qb,        // [128][NPAD][64]  (q pre-scaled by SCALE_Q)
    unsigned short* __restrict__ kb,        // [128][NPAD][64]
    unsigned short* __restrict__ vb)        // [128][NTOK][64]  (normal layout; transposed later)
{
  const int K = 1024;
  __shared__ __align__(16) unsigned short As[2][128*32];
  __shared__ __align__(16) unsigned short Bs[2][128*32];
  int tid = threadIdx.x;
  int id = blockIdx.x;
  int work = (id & 7) * 195 + (id >> 3);
  int m0 = (work / 24) * 128, n0 = (work % 24) * 128;
  int w = tid >> 6, lane = tid & 63, lr = lane & 15, lg = lane >> 4;
  int wr = w >> 1, wc = w & 1;
  int srow = lane >> 2;
  // source pre-swizzle: slot' = slot ^ ((row>>1)&3); row bits1-2 == srow bits1-2
  int scol = ((lane & 3) ^ ((lane >> 3) & 3)) * 8;
  // read swizzle (same involution): row bits1-2 == lr bits1-2
  int sa = (lg ^ ((lr >> 1) & 3)) * 8;
  f32x4 acc[4][4] = {};

  // prologue: stage k-tile 0 into buf 0 (4 loads/wave)
  #pragma unroll
  for (int i = 0; i < 2; i++){
    int q = w * 2 + i;
    gl_lds16(&A [(size_t)(m0 + q*16 + srow) * K + scol], &As[0][q*512]);
    gl_lds16(&Bw[(size_t)(n0 + q*16 + srow) * K + scol], &Bs[0][q*512]);
  }

  for (int kt = 0; kt < 32; kt++){
    int cur = kt & 1;
    if (kt < 31){
      int k0 = (kt + 1) * 32;
      #pragma unroll
      for (int i = 0; i < 2; i++){
        int q = w * 2 + i;
        gl_lds16(&A [(size_t)(m0 + q*16 + srow) * K + k0 + scol], &As[cur^1][q*512]);
        gl_lds16(&Bw[(size_t)(n0 + q*16 + srow) * K + k0 + scol], &Bs[cur^1][q*512]);
      }
      asm volatile("s_waitcnt vmcnt(4)" ::: "memory");   // drain cur tile only; next stays in flight
    } else {
      asm volatile("s_waitcnt vmcnt(0)" ::: "memory");
    }
    __builtin_amdgcn_sched_barrier(0);
    __builtin_amdgcn_s_barrier();                        // cur tile visible to all waves

    us8 a[4], b[4];
    #pragma unroll
    for (int mi = 0; mi < 4; mi++) a[mi] = *reinterpret_cast<const us8*>(&As[cur][(wr*64 + mi*16 + lr)*32 + sa]);
    #pragma unroll
    for (int ni = 0; ni < 4; ni++) b[ni] = *reinterpret_cast<const us8*>(&Bs[cur][(wc*64 + ni*16 + lr)*32 + sa]);
    #pragma unroll
    for (int mi = 0; mi < 4; mi++)
      #pragma unroll
      for (int ni = 0; ni < 4; ni++)
        acc[mi][ni] = MFMA16(a[mi], b[ni], acc[mi][ni]);
    __builtin_amdgcn_s_barrier();                        // reads done; next iter may overwrite cur^1... (dbuf safe)
  }

  // epilogue: q/k into padded [bh][n][64]; v into normal [bh][n][64]
  #pragma unroll
  for (int mi = 0; mi < 4; mi++){
    #pragma unroll
    for (int ni = 0; ni < 4; ni++){
      #pragma unroll
      for (int reg = 0; reg < 4; reg++){
        int m = m0 + wr*64 + mi*16 + lg*4 + reg;
        if (m >= MTOT) continue;
        int n = n0 + wc*64 + ni*16 + lr;
        float val = acc[mi][ni][reg] + bias[n];
        int b_ = m / NTOK, nidx = m % NTOK;
        int t = n >> 10, h = (n >> 6) & 15, d = n & 63;
        int bh = h * BATCH + b_;
        if (t == 0){
          qb[(size_t)(bh * NPAD + nidx) * 64 + d] = f2bf(val * SCALE_Q);
        } else if (t == 1){
          kb[(size_t)(bh * NPAD + nidx) * 64 + d] = f2bf(val);
        } else {
          vb[(size_t)(bh * NTOK + nidx) * 64 + d] = f2bf(val);
        }
      }
    }
  }
}

// ---------------- V transpose: vb [bh][n][64] -> vt [bh][64][NPAD] ----------------
__global__ __launch_bounds__(256) void transpose_v(const unsigned short* __restrict__ vb,
                                                   unsigned short* __restrict__ vt){
  __shared__ unsigned short Ls[64][72];
  int blk = blockIdx.x;
  int bh = blk / 17, tl = blk % 17;       // 17 tiles cover keys 0..1088
  int n0 = tl * 64;
  int t = threadIdx.x;

  #pragma unroll
  for (int p = 0; p < 2; p++){
    int idx = p * 256 + t;                // 512 chunks: r = idx>>3, c = idx&7
    int r = idx >> 3, c = idx & 7;
    us8 v = {};
    if (n0 + r < NTOK)
      v = *reinterpret_cast<const us8*>(&vb[((size_t)bh * NTOK + n0 + r) * 64 + c * 8]);
    *reinterpret_cast<us8*>(&Ls[r][c * 8]) = v;
  }
  __syncthreads();

  int d = t & 63, ng = t >> 6;            // each thread: row d, 16 n-values
  us8 o[2];
  #pragma unroll
  for (int hf = 0; hf < 2; hf++){
    #pragma unroll
    for (int j = 0; j < 8; j++) o[hf][j] = Ls[ng*16 + hf*8 + j][d];
    *reinterpret_cast<us8*>(&vt[((size_t)bh * 64 + d) * NPAD + n0 + ng*16 + hf*8]) = o[hf];
  }
}

// ---------------- flash attention v6: v5 + counted-vmcnt pipeline ----------------
__global__ __launch_bounds__(256,3) void attn_kernel(
    const unsigned short* __restrict__ qb,
    const unsigned short* __restrict__ kb,
    const unsigned short* __restrict__ vt,
    const float* __restrict__ rph,   // [63][64]
    const float* __restrict__ rpw,   // [63][64]
    unsigned short* __restrict__ ao) // [MPAD][1024], rows b*NTOK+n
{
  __shared__ __align__(16) unsigned short Ks[2][64*64];   // 16 KB, XOR-swizzled chunks
  __shared__ __align__(16) unsigned short Vs[2][64*64];   // 16 KB
  __shared__ unsigned short RHt[32*128];                  // [kh][qrow] bf16 (x log2e)
  __shared__ unsigned short RWc[32*128];                  // [kw][qrow] bf16 (x log2e)

  int id = blockIdx.x;
  int work = (id & 7) * 144 + (id >> 3);
  int bh = work / 9;            // 0..127
  int qt = work % 9;            // 0..8 (128 q-rows each)
  int tid = threadIdx.x, w = tid >> 6, lane = tid & 63, lr = lane & 15, lg = lane >> 4;
  int h = bh >> 3, b_ = bh & 7;

  const unsigned short* qbase = qb + (size_t)bh * NPAD * 64;
  const unsigned short* kbase = kb + (size_t)bh * NPAD * 64;
  const unsigned short* vbase = vt + (size_t)bh * 64 * NPAD;

  // ---- stage kt=0 ----
  #pragma unroll
  for (int t = 0; t < 2; t++){
    int i = t*256 + tid;
    int row = i >> 3, cs = (i & 7) ^ (row & 7);
    gl_lds16(&kbase[(size_t)row*64 + cs*8],   &Ks[0][(t*256 + w*64)*8]);
    gl_lds16(&vbase[(size_t)row*NPAD + cs*8], &Vs[0][(t*256 + w*64)*8]);
  }

  // ---- Q fragments (B-operand of swapped QK^T): wave w owns q-rows [w*32, w*32+32) ----
  us8 aq[2][2];
  #pragma unroll
  for (int qf = 0; qf < 2; qf++){
    int qrow = qt*128 + w*32 + qf*16 + lr;
    aq[qf][0] = *reinterpret_cast<const us8*>(&qbase[(size_t)qrow*64 + lg*8]);
    aq[qf][1] = *reinterpret_cast<const us8*>(&qbase[(size_t)qrow*64 + 32 + lg*8]);
  }

  float rwreg[2][2][4] = {};   // [qf][kw>=16][reg], preloaded (kt-independent)

  // ---- rel-pos tables, transposed: RHt[kh][qrow], RWc[kw][qrow] ----
  if (qt < 8){
    int qh = qt*4 + w;     // wave-uniform
    f32x4 accH[2][2] = {};
    #pragma unroll
    for (int ks = 0; ks < 2; ks++){
      #pragma unroll
      for (int nf2 = 0; nf2 < 2; nf2++){
        int t = nf2*16 + lr;
        const float* src = rph + (size_t)(qh - t + 31)*64 + ks*32 + lg*8;
        us8 ar;
        #pragma unroll
        for (int j = 0; j < 8; j++) ar[j] = f2bf(src[j]);
        #pragma unroll
        for (int qf = 0; qf < 2; qf++) accH[qf][nf2] = MFMA16(ar, aq[qf][ks], accH[qf][nf2]);
      }
    }
    #pragma unroll
    for (int qf = 0; qf < 2; qf++)
      #pragma unroll
      for (int nf2 = 0; nf2 < 2; nf2++)
        #pragma unroll
        for (int reg = 0; reg < 4; reg++){
          int t_out = nf2*16 + lg*4 + reg;        // kh 0..31
          RHt[t_out*128 + w*32 + qf*16 + lr] = f2bf(accH[qf][nf2][reg] * 8.0f);
        }
    f32x4 accW[2][4] = {};
    #pragma unroll
    for (int ks = 0; ks < 2; ks++){
      #pragma unroll
      for (int nf = 0; nf < 4; nf++){
        int t = nf*16 + lr;
        us8 aw_ = {};
        if (t < 63){
          const float* src = rpw + (size_t)t*64 + ks*32 + lg*8;
          #pragma unroll
          for (int j = 0; j < 8; j++) aw_[j] = f2bf(src[j]);
        }
        #pragma unroll
        for (int qf = 0; qf < 2; qf++) accW[qf][nf] = MFMA16(aw_, aq[qf][ks], accW[qf][nf]);
      }
    }
    #pragma unroll
    for (int qf = 0; qf < 2; qf++)
      #pragma unroll
      for (int nf = 0; nf < 4; nf++)
        #pragma unroll
        for (int reg = 0; reg < 4; reg++){
          int t_out = nf*16 + lg*4 + reg;
          int qw = qf*16 + lr;                     // qrow & 31
          int kw = qw - t_out + 31;
          if (kw >= 0 && kw < 32)
            RWc[kw*128 + w*32 + qf*16 + lr] = f2bf(accW[qf][nf][reg] * 8.0f);
        }
    // preload RW into regs (own-wave LDS, in-wave ordering suffices)
    #pragma unroll
    for (int qf = 0; qf < 2; qf++)
      #pragma unroll
      for (int hf = 0; hf < 2; hf++)
        #pragma unroll
        for (int reg = 0; reg < 4; reg++)
          rwreg[qf][hf][reg] = bf2f(RWc[(hf*16 + lg*4 + reg)*128 + w*32 + qf*16 + lr]);
  }
  __syncthreads();   // full drain once: tables + stage-0 visible

  f32x4 O[2][4] = {};
  f32x4 lac[2] = {};
  s4 ones4;
  ones4.x = (short)0x3F80; ones4.y = (short)0x3F80; ones4.z = (short)0x3F80; ones4.w = (short)0x3F80;

  for (int kt = 0; kt < 17; kt++){
    int cur = kt & 1;
    if (kt < 16){
      #pragma unroll
      for (int t = 0; t < 2; t++){
        int i = t*256 + tid;
        int row = i >> 3, cs = (i & 7) ^ (row & 7);
        gl_lds16(&kbase[(size_t)((kt+1)*64 + row)*64 + cs*8], &Ks[cur^1][(t*256 + w*64)*8]);
        gl_lds16(&vbase[(size_t)row*NPAD + (kt+1)*64 + cs*8], &Vs[cur^1][(t*256 + w*64)*8]);
      }
      asm volatile("s_waitcnt vmcnt(4)" ::: "memory");   // cur tile done; next stays in flight
    } else {
      asm volatile("s_waitcnt vmcnt(0)" ::: "memory");
    }
    __builtin_amdgcn_sched_barrier(0);
    __builtin_amdgcn_s_barrier();

    // ---- swapped QK^T: St[key][qrow] = K x Q^T ----
    f32x4 S[2][4] = {};
    __builtin_amdgcn_s_setprio(1);
    #pragma unroll
    for (int ks = 0; ks < 2; ks++)
      #pragma unroll
      for (int nf = 0; nf < 4; nf++){
        us8 bk = *reinterpret_cast<const us8*>(
            &Ks[cur][(nf*16 + lr)*64 + (((ks*4 + lg) ^ (lr & 7)) * 8)]);
        S[0][nf] = MFMA16(bk, aq[0][ks], S[0][nf]);
        S[1][nf] = MFMA16(bk, aq[1][ks], S[1][nf]);
      }
    __builtin_amdgcn_s_setprio(0);

    // ---- softmax (no-max): p = exp2(St + bias'), pack to bf16x4 A-frags in-register ----
    bool gk = (qt < 8) && (kt < 16);
    float rh2[2][2];
    #pragma unroll
    for (int qf = 0; qf < 2; qf++)
      #pragma unroll
      for (int hf = 0; hf < 2; hf++)
        rh2[qf][hf] = gk ? (bf2f(RHt[(kt*2 + hf)*128 + w*32 + qf*16 + lr]) - C2) : -C2;

    s4 pa[2][4];
    #pragma unroll
    for (int qf = 0; qf < 2; qf++){
      #pragma unroll
      for (int nf = 0; nf < 4; nf++){
        float pv[4];
        #pragma unroll
        for (int reg = 0; reg < 4; reg++){
          float logit = S[qf][nf][reg] + rh2[qf][nf>>1] + (gk ? rwreg[qf][nf&1][reg] : 0.f);
          float p = __builtin_amdgcn_exp2f(logit);
          int key = kt*64 + nf*16 + lg*4 + reg;
          pv[reg] = (key < NTOK) ? p : 0.f;
        }
        unsigned int u0 = __builtin_amdgcn_perm(
            __builtin_bit_cast(unsigned int, pv[1]), __builtin_bit_cast(unsigned int, pv[0]), 0x07060302u);
        unsigned int u1 = __builtin_amdgcn_perm(
            __builtin_bit_cast(unsigned int, pv[3]), __builtin_bit_cast(unsigned int, pv[2]), 0x07060302u);
        uint2 uu; uu.x = u0; uu.y = u1;
        pa[qf][nf] = __builtin_bit_cast(s4, uu);
      }
    }

    // ---- PV + l: K=16 MFMAs, P straight from registers ----
    __builtin_amdgcn_s_setprio(1);
    #pragma unroll
    for (int qf = 0; qf < 2; qf++)
      #pragma unroll
      for (int nf = 0; nf < 4; nf++)
        lac[qf] = MFMAH(pa[qf][nf], ones4, lac[qf]);
    #pragma unroll
    for (int nf = 0; nf < 4; nf++){
      #pragma unroll
      for (int nfd = 0; nfd < 4; nfd++){
        us4 bv = *reinterpret_cast<const us4*>(
            &Vs[cur][(nfd*16 + lr)*64 + (((nf*2 + (lg>>1)) ^ (lr & 7))*8) + (lg&1)*4]);
        O[0][nfd] = MFMAH(pa[0][nf], bv, O[0][nfd]);
        O[1][nfd] = MFMAH(pa[1][nf], bv, O[1][nfd]);
      }
    }
    __builtin_amdgcn_s_setprio(0);
    __builtin_amdgcn_s_barrier();    // reads of cur done; next iter overwrites it
  }

  // ---- epilogue: O rows = qrow (lg*4+reg), cols = d (lr). lac aligned with O rows. ----
  #pragma unroll
  for (int qf = 0; qf < 2; qf++)
    #pragma unroll
    for (int reg = 0; reg < 4; reg++){
      int qg = qt*128 + w*32 + qf*16 + lg*4 + reg;
      if (qg < NTOK){
        float inv = 1.0f / lac[qf][reg];
        #pragma unroll
        for (int nfd = 0; nfd < 4; nfd++)
          ao[(size_t)(b_ * NTOK + qg) * 1024 + h*64 + nfd*16 + lr] = f2bf(O[qf][nfd][reg] * inv);
      }
    }
}

// ---------------- proj GEMM (counted-vmcnt 2-phase + swizzled LDS + XCD swizzle) ----------------
__global__ __launch_bounds__(256,4) void proj_gemm(
    const unsigned short* __restrict__ A,   // [MPAD][1024]
    const unsigned short* __restrict__ Bw,  // [1024][1024]
    const float* __restrict__ bias,
    float* __restrict__ out)
{
  const int K = 1024;
  __shared__ __align__(16) unsigned short As[2][128*32];
  __shared__ __align__(16) unsigned short Bs[2][128*32];
  int tid = threadIdx.x;
  int id = blockIdx.x;
  int work = (id & 7) * 65 + (id >> 3);
  int m0 = (work / 8) * 128, n0 = (work % 8) * 128;
  int w = tid >> 6, lane = tid & 63, lr = lane & 15, lg = lane >> 4;
  int wr = w >> 1, wc = w & 1;
  int srow = lane >> 2;
  int scol = ((lane & 3) ^ ((lane >> 3) & 3)) * 8;
  int sa = (lg ^ ((lr >> 1) & 3)) * 8;
  f32x4 acc[4][4] = {};

  #pragma unroll
  for (int i = 0; i < 2; i++){
    int q = w * 2 + i;
    gl_lds16(&A [(size_t)(m0 + q*16 + srow) * K + scol], &As[0][q*512]);
    gl_lds16(&Bw[(size_t)(n0 + q*16 + srow) * K + scol], &Bs[0][q*512]);
  }

  for (int kt = 0; kt < 32; kt++){
    int cur = kt & 1;
    if (kt < 31){
      int k0 = (kt + 1) * 32;
      #pragma unroll
      for (int i = 0; i < 2; i++){
        int q = w * 2 + i;
        gl_lds16(&A [(size_t)(m0 + q*16 + srow) * K + k0 + scol], &As[cur^1][q*512]);
        gl_lds16(&Bw[(size_t)(n0 + q*16 + srow) * K + k0 + scol], &Bs[cur^1][q*512]);
      }
      asm volatile("s_waitcnt vmcnt(4)" ::: "memory");
    } else {
      asm volatile("s_waitcnt vmcnt(0)" ::: "memory");
    }
    __builtin_amdgcn_sched_barrier(0);
    __builtin_amdgcn_s_barrier();

    us8 a[4], b[4];
    #pragma unroll
    for (int mi = 0; mi < 4; mi++) a[mi] = *reinterpret_cast<const us8*>(&As[cur][(wr*64 + mi*16 + lr)*32 + sa]);
    #pragma unroll
    for (int ni = 0; ni < 4; ni++) b[ni] = *reinterpret_cast<const us8*>(&Bs[cur][(wc*64 + ni*16 + lr)*32 + sa]);
    #pragma unroll
    for (int mi = 0; mi < 4; mi++)
      #pragma unroll
      for (int ni = 0; ni < 4; ni++)
        acc[mi][ni] = MFMA16(a[mi], b[ni], acc[mi][ni]);
    __builtin_amdgcn_s_barrier();
  }

  #pragma unroll
  for (int mi = 0; mi < 4; mi++){
    #pragma unroll
    for (int ni = 0; ni < 4; ni++){
      #pragma unroll
      for (int reg = 0; reg < 4; reg++){
        int m = m0 + wr*64 + mi*16 + lg*4 + reg;
        if (m >= MTOT) continue;
        int n = n0 + wc*64 + ni*16 + lr;
        out[(size_t)m * 1024 + n] = acc[mi][ni][reg] + bias[n];
      }
    }
  }
}

extern "C" void kernel_launch(void* const* d_in, const int* in_sizes, int n_in,
                              void* d_out, int out_size, void* d_ws, size_t ws_size,
                              hipStream_t stream)
{
  const float* x      = (const float*)d_in[0];
  const float* qkv_w  = (const float*)d_in[1];
  const float* qkv_b  = (const float*)d_in[2];
  const float* proj_w = (const float*)d_in[3];
  const float* proj_b = (const float*)d_in[4];
  const float* rph    = (const float*)d_in[5];
  const float* rpw    = (const float*)d_in[6];
  float* out = (float*)d_out;

  char* ws = (char*)d_ws;
  size_t off = 0;
  auto alloc = [&](size_t bytes){ char* p = ws + off; off += (bytes + 255) & ~(size_t)255; return p; };
  unsigned short* x_bf  = (unsigned short*)alloc((size_t)MPAD * 1024 * 2);
  unsigned short* qw_bf = (unsigned short*)alloc((size_t)3072 * 1024 * 2);
  unsigned short* pw_bf = (unsigned short*)alloc((size_t)1024 * 1024 * 2);
  unsigned short* qbuf  = (unsigned short*)alloc((size_t)128 * NPAD * 64 * 2);
  unsigned short* kbuf  = (unsigned short*)alloc((size_t)128 * NPAD * 64 * 2);
  unsigned short* vtbuf = (unsigned short*)alloc((size_t)128 * 64 * NPAD * 2);
  unsigned short* aout  = (unsigned short*)alloc((size_t)MPAD * 1024 * 2);
  if (off > ws_size) return;   // workspace too small: fail visibly

  // vb (normal-layout V) aliases the head of aout: written by qkv_gemm,
  // consumed by transpose_v BEFORE attn writes aout.
  unsigned short* vbuf = aout;

  int n4x = MTOT * 1024 / 4;
  cvt_f32_bf16<<<dim3((n4x + 255) / 256), 256, 0, stream>>>(x, x_bf, n4x);
  int n4q = 3072 * 1024 / 4;
  cvt_f32_bf16<<<dim3((n4q + 255) / 256), 256, 0, stream>>>(qkv_w, qw_bf, n4q);
  int n4p = 1024 * 1024 / 4;
  cvt_f32_bf16<<<dim3((n4p + 255) / 256), 256, 0, stream>>>(proj_w, pw_bf, n4p);

  int npad = 128 * (NPAD - NTOK) * 64 + 2 * (MPAD - MTOT) * 1024;
  pad_zero<<<dim3((npad + 255) / 256), 256, 0, stream>>>(qbuf, kbuf, x_bf, aout);

  qkv_gemm<<<dim3(1560), 256, 0, stream>>>(x_bf, qw_bf, qkv_b, qbuf, kbuf, vbuf);
  transpose_v<<<dim3(128 * 17), 256, 0, stream>>>(vbuf, vtbuf);
  attn_kernel<<<dim3(1152), 256, 0, stream>>>(qbuf, kbuf, vtbuf, rph, rpw, aout);
  proj_gemm<<<dim3(520), 256, 0, stream>>>(aout, pw_bf, proj_b, out);
}